// Round 2
// baseline (1911.858 us; speedup 1.0000x reference)
//
#include <hip/hip_runtime.h>
#include <math.h>

#define B_   256
#define NLAB 20000
#define M_   3
#define D_   768
#define T_   5
#define K_   8
#define H_   256
#define DI_  512
#define S_   16
#define R_   16
#define NL_  4
#define KC_  4
#define L_   9          // K+1 tokens
#define NBT  1280       // B*T sequences
#define NROW 11520      // NBT*L flattened rows

typedef __attribute__((ext_vector_type(8))) short bf16x8;
typedef __attribute__((ext_vector_type(4))) float floatx4;

// ---------------- helpers ----------------

__device__ __forceinline__ float block_reduce_sum(float v) {
    __shared__ float red[4];
    int lane = threadIdx.x & 63;
    int wid  = threadIdx.x >> 6;
#pragma unroll
    for (int o = 32; o > 0; o >>= 1) v += __shfl_down(v, o);
    if (lane == 0) red[wid] = v;
    __syncthreads();
    int nw = (int)(blockDim.x >> 6);
    float r = 0.f;
#pragma unroll
    for (int i = 0; i < 4; ++i) if (i < nw) r += red[i];
    __syncthreads();
    return r;
}

__device__ __forceinline__ float sigmoidf_(float x) { return 1.f / (1.f + expf(-x)); }
__device__ __forceinline__ float siluf_(float x)    { return x * sigmoidf_(x); }
__device__ __forceinline__ float softplusf_(float x){ return x > 20.f ? x : log1pf(expf(x)); }

// round-to-nearest-even fp32 -> bf16 bits
__device__ __forceinline__ unsigned short f2bf(float x) {
    unsigned u = __float_as_uint(x);
    unsigned r = (u + 0x7fffu + ((u >> 16) & 1u)) >> 16;
    return (unsigned short)r;
}
__device__ __forceinline__ float bf2f(unsigned short h) {
    return __uint_as_float(((unsigned)h) << 16);
}

// barrier that does NOT drain vmcnt: LDS ordering only.  Global register loads
// issued before this stay in flight across the barrier (T3/T4 counted-wait).
__device__ __forceinline__ void barrier_lds_only() {
    asm volatile("s_waitcnt lgkmcnt(0)" ::: "memory");
    __builtin_amdgcn_s_barrier();
}

// ---------------- kernels ----------------

__global__ void k_softmax_w(const float* __restrict__ mlog, float* __restrict__ w) {
    int t = threadIdx.x;
    if (t < T_) {
        float a = mlog[t*M_+0], b = mlog[t*M_+1], c = mlog[t*M_+2];
        float mx = fmaxf(a, fmaxf(b, c));
        float ea = expf(a-mx), eb = expf(b-mx), ec = expf(c-mx);
        float s = ea + eb + ec;
        w[t*M_+0] = ea/s; w[t*M_+1] = eb/s; w[t*M_+2] = ec/s;
    }
}

// qn (normalized queries) -> bf16 hi/lo planes ; uc = mean over m
__global__ __launch_bounds__(256) void k_qn_uc(const float* __restrict__ unl,
                                               const float* __restrict__ w,
                                               unsigned short* __restrict__ qnh,
                                               unsigned short* __restrict__ qnl,
                                               float* __restrict__ uc) {
    int b = blockIdx.x, tid = threadIdx.x;
    float e[3][3];
#pragma unroll
    for (int c = 0; c < 3; ++c) {
        int d = tid + c*256;
#pragma unroll
        for (int m = 0; m < 3; ++m)
            e[c][m] = unl[((size_t)b*3 + m)*D_ + d];
    }
#pragma unroll
    for (int c = 0; c < 3; ++c)
        uc[(size_t)b*D_ + tid + c*256] = (e[c][0] + e[c][1] + e[c][2]) * (1.f/3.f);
    for (int t = 0; t < T_; ++t) {
        float w0 = w[t*3+0], w1 = w[t*3+1], w2 = w[t*3+2];
        float q[3]; float ss = 0.f;
#pragma unroll
        for (int c = 0; c < 3; ++c) {
            q[c] = w0*e[c][0] + w1*e[c][1] + w2*e[c][2];
            ss += q[c]*q[c];
        }
        float tot = block_reduce_sum(ss);
        float inv = rsqrtf(tot + 1e-8f);
#pragma unroll
        for (int c = 0; c < 3; ++c) {
            float v = q[c]*inv;
            size_t o = ((size_t)t*B_ + b)*D_ + tid + c*256;
            unsigned short h = f2bf(v);
            qnh[o] = h; qnl[o] = f2bf(v - bf2f(h));
        }
    }
}

// weight+ssq+split-bf16 convert of one staged row chunk, store to LDS
__device__ __forceinline__ void cvt_store4(const float4* rb, float w0, float w1, float w2,
                                           unsigned short* bh, unsigned short* bl,
                                           int off, float& ss) {
    float4 s;
    s.x = w0*rb[0].x + w1*rb[1].x + w2*rb[2].x;
    s.y = w0*rb[0].y + w1*rb[1].y + w2*rb[2].y;
    s.z = w0*rb[0].z + w1*rb[1].z + w2*rb[2].z;
    s.w = w0*rb[0].w + w1*rb[1].w + w2*rb[2].w;
    ss += s.x*s.x + s.y*s.y + s.z*s.z + s.w*s.w;
    ushort4 h, l;
    h.x = f2bf(s.x); l.x = f2bf(s.x - bf2f(h.x));
    h.y = f2bf(s.y); l.y = f2bf(s.y - bf2f(h.y));
    h.z = f2bf(s.z); l.z = f2bf(s.z - bf2f(h.z));
    h.w = f2bf(s.w); l.w = f2bf(s.w - bf2f(h.w));
    *(ushort4*)(bh + off) = h;
    *(ushort4*)(bl + off) = l;
}

// split-bf16 MFMA sim GEMM, BM=256 (all b), BN=128, BK=32; 512 threads / 8 waves.
// - A fragments read directly from global (qn planes, L2-hot)
// - B staged in ping-pong LDS (2 x 20.5 KB); ONE barrier per K-tile
// - barrier does not drain vmcnt -> raw-B register prefetch + A loads stay in
//   flight across it (the round-1 __syncthreads drained them = the regression)
// - XCD-swizzled 1-D grid: the 5 t-blocks sharing a lab_e slice run adjacently
//   on the same XCD -> L2 reuse instead of 5x L3/HBM re-reads
// - row norms (rn) fused: ssq of weighted rows + 8-lane shfl reduce
__global__ __launch_bounds__(512, 4) void k_simf(const unsigned short* __restrict__ qnh,
                                                 const unsigned short* __restrict__ qnl,
                                                 const float* __restrict__ lab_e,
                                                 const float* __restrict__ w,
                                                 float* __restrict__ sim) {
    __shared__ unsigned short Bh[2*128*40], Bl[2*128*40];
    __shared__ float rnl[128];
    // XCD-aware work assignment: 157 bn-chunks split across 8 XCDs, t innermost
    int bid = blockIdx.x;
    int xcd = bid & 7, s = bid >> 3;
    int cnt = (xcd < 5) ? 20 : 19;                  // bn-chunks owned by this xcd
    if (s >= cnt * 5) return;
    int start = (xcd < 5) ? xcd*20 : 100 + (xcd-5)*19;
    int bnc = start + s / 5;
    int t = s - (s/5)*5;
    int bn = bnc * 128;

    float w0 = w[t*3+0], w1 = w[t*3+1], w2 = w[t*3+2];
    int tid = threadIdx.x;
    int lane = tid & 63, wv = tid >> 6;
    int mbase = (wv >> 1)*64, nbase = (wv & 1)*64;
    int fr = lane & 15, kg = lane >> 4;

    // B staging role: two rows per thread (gr0, gr1), 4-col chunk kq
    int gr0 = tid >> 3, gr1 = 64 + (tid >> 3), kq = tid & 7;
    int gn0 = bn + gr0, gn1 = bn + gr1;
    bool v0 = gn0 < NLAB, v1 = gn1 < NLAB;
    const float* bp0 = lab_e + (size_t)gn0*(3*D_) + kq*4;
    const float* bp1 = lab_e + (size_t)gn1*(3*D_) + kq*4;

    floatx4 acc[4][4];
#pragma unroll
    for (int mi = 0; mi < 4; ++mi)
#pragma unroll
        for (int ni = 0; ni < 4; ++ni)
            acc[mi][ni] = (floatx4){0.f, 0.f, 0.f, 0.f};

    float ss0 = 0.f, ss1 = 0.f;
    float4 rb0[3], rb1[3];
    float4 z4 = make_float4(0.f, 0.f, 0.f, 0.f);
    rb0[0]=rb0[1]=rb0[2]=z4; rb1[0]=rb1[1]=rb1[2]=z4;
    if (v0) { rb0[0] = *(const float4*)(bp0);
              rb0[1] = *(const float4*)(bp0 + D_);
              rb0[2] = *(const float4*)(bp0 + 2*D_); }
    if (v1) { rb1[0] = *(const float4*)(bp1);
              rb1[1] = *(const float4*)(bp1 + D_);
              rb1[2] = *(const float4*)(bp1 + 2*D_); }
    // prologue: convert tile 0 into buffer 0
    cvt_store4(rb0, w0, w1, w2, Bh, Bl, gr0*40 + kq*4, ss0);
    cvt_store4(rb1, w0, w1, w2, Bh, Bl, gr1*40 + kq*4, ss1);

    const unsigned short* aph = qnh + ((size_t)t*B_ + mbase + fr)*D_ + kg*8;
    const unsigned short* apl = qnl + ((size_t)t*B_ + mbase + fr)*D_ + kg*8;

    for (int kt = 0; kt < 24; ++kt) {
        int cur = kt & 1;
        const unsigned short* bhr = Bh + cur*5120;
        const unsigned short* blr = Bl + cur*5120;
        unsigned short* bhw = Bh + (cur^1)*5120;
        unsigned short* blw = Bl + (cur^1)*5120;
        int k0 = kt*32;

        // A fragment loads for THIS tile — issued first so the MFMA's vmcnt
        // wait retires without draining the rb prefetch behind it
        bf16x8 ahf[4], alf[4];
#pragma unroll
        for (int mi = 0; mi < 4; ++mi) {
            ahf[mi] = *(const bf16x8*)(aph + (size_t)mi*16*D_ + k0);
            alf[mi] = *(const bf16x8*)(apl + (size_t)mi*16*D_ + k0);
        }
        // raw-B register prefetch for tile kt+1 — flies across the barrier
        if (kt < 23) {
            const float* p0 = bp0 + k0 + 32;
            const float* p1 = bp1 + k0 + 32;
            if (v0) { rb0[0] = *(const float4*)(p0);
                      rb0[1] = *(const float4*)(p0 + D_);
                      rb0[2] = *(const float4*)(p0 + 2*D_); }
            if (v1) { rb1[0] = *(const float4*)(p1);
                      rb1[1] = *(const float4*)(p1 + D_);
                      rb1[2] = *(const float4*)(p1 + 2*D_); }
        }

        barrier_lds_only();        // buf[cur] writes (prev iter) now visible

        bf16x8 bhf[4], blf[4];
#pragma unroll
        for (int ni = 0; ni < 4; ++ni) {
            int off = (nbase + ni*16 + fr)*40 + kg*8;
            bhf[ni] = *(const bf16x8*)(bhr + off);
            blf[ni] = *(const bf16x8*)(blr + off);
        }
#pragma unroll
        for (int mi = 0; mi < 4; ++mi) {
#pragma unroll
            for (int ni = 0; ni < 4; ++ni) {
                floatx4 c = acc[mi][ni];
                c = __builtin_amdgcn_mfma_f32_16x16x32_bf16(ahf[mi], bhf[ni], c, 0, 0, 0);
                c = __builtin_amdgcn_mfma_f32_16x16x32_bf16(alf[mi], bhf[ni], c, 0, 0, 0);
                c = __builtin_amdgcn_mfma_f32_16x16x32_bf16(ahf[mi], blf[ni], c, 0, 0, 0);
                acc[mi][ni] = c;
            }
        }
        // convert tile kt+1 into the other buffer (read next iter, after barrier)
        if (kt < 23) {
            cvt_store4(rb0, w0, w1, w2, bhw, blw, gr0*40 + kq*4, ss0);
            cvt_store4(rb1, w0, w1, w2, bhw, blw, gr1*40 + kq*4, ss1);
        }
    }

    // fold rn: reduce ssq across the 8 threads of each row
    float t0 = ss0, t1 = ss1;
#pragma unroll
    for (int m = 1; m <= 4; m <<= 1) { t0 += __shfl_xor(t0, m); t1 += __shfl_xor(t1, m); }
    if ((tid & 7) == 0) {
        rnl[tid >> 3]        = rsqrtf(t0 + 1e-8f);
        rnl[64 + (tid >> 3)] = rsqrtf(t1 + 1e-8f);
    }
    __syncthreads();

    float* st = sim + (size_t)t*B_*NLAB;
#pragma unroll
    for (int mi = 0; mi < 4; ++mi) {
        int m = mbase + mi*16 + kg*4;
#pragma unroll
        for (int ni = 0; ni < 4; ++ni) {
            int nl = nbase + ni*16 + fr;
            int n = bn + nl;
            if (n < NLAB) {
                float rv = rnl[nl];
#pragma unroll
                for (int r = 0; r < 4; ++r)
                    st[(size_t)(m + r)*NLAB + n] = acc[mi][ni][r] * rv;
            }
        }
    }
}

// per-row top-8, grid (B, T)
__global__ __launch_bounds__(256) void k_topk(const float* __restrict__ sim,
                                              int* __restrict__ idx_out) {
    int b = blockIdx.x;
    int t = blockIdx.y;
    int tid = threadIdx.x;
    const float* row = sim + ((size_t)t*B_ + b)*NLAB;
    float tv[8]; int ti[8];
#pragma unroll
    for (int k = 0; k < 8; ++k) { tv[k] = -3e38f; ti[k] = 0x7fffffff; }
    for (int n = tid; n < NLAB; n += 256) {
        float v = row[n];
        if (v > tv[7]) {
            tv[7] = v; ti[7] = n;
#pragma unroll
            for (int k = 7; k > 0; --k) {
                if (tv[k] > tv[k-1]) {
                    float fv = tv[k]; tv[k] = tv[k-1]; tv[k-1] = fv;
                    int fi = ti[k]; ti[k] = ti[k-1]; ti[k-1] = fi;
                }
            }
        }
    }
    __shared__ float sv[2048];
    __shared__ int   si[2048];
    __shared__ float pv[256];
    __shared__ int   pi[256];
    __shared__ int   pp[256];
#pragma unroll
    for (int k = 0; k < 8; ++k) { sv[tid*8+k] = tv[k]; si[tid*8+k] = ti[k]; }
    __syncthreads();
    for (int r = 0; r < 8; ++r) {
        float bv = -3e38f; int bi = 0x7fffffff; int bp = 0;
#pragma unroll
        for (int k = 0; k < 8; ++k) {
            int p = tid*8 + k;
            float v = sv[p]; int ii = si[p];
            if (v > bv || (v == bv && ii < bi)) { bv = v; bi = ii; bp = p; }
        }
        pv[tid] = bv; pi[tid] = bi; pp[tid] = bp;
        __syncthreads();
        for (int off = 128; off > 0; off >>= 1) {
            if (tid < off) {
                if (pv[tid+off] > pv[tid] || (pv[tid+off] == pv[tid] && pi[tid+off] < pi[tid])) {
                    pv[tid] = pv[tid+off]; pi[tid] = pi[tid+off]; pp[tid] = pp[tid+off];
                }
            }
            __syncthreads();
        }
        if (tid == 0) {
            idx_out[((size_t)b*T_ + t)*K_ + r] = pi[0];
            sv[pp[0]] = -3e38f;
        }
        __syncthreads();
    }
}

// build token planes (bf16 hi/lo, 768 cols) + trait vector tt
__global__ __launch_bounds__(256) void k_toks(const float* __restrict__ lab_e,
                                              const float* __restrict__ lab_t,
                                              const float* __restrict__ uc,
                                              const int* __restrict__ idx,
                                              unsigned short* __restrict__ tokh,
                                              unsigned short* __restrict__ tokl,
                                              float* __restrict__ tt) {
    int g = blockIdx.x;            // 0..NROW-1
    int bt = g / L_, l = g % L_;
    int b = bt / T_, t = bt % T_;
    size_t ro = (size_t)g*D_;
    if (l < K_) {
        int n = idx[(size_t)bt*K_ + l];
        for (int d = threadIdx.x; d < D_; d += 256) {
            size_t base = (size_t)n*(3*D_) + d;
            float v = (lab_e[base] + lab_e[base + D_] + lab_e[base + 2*D_]) * (1.f/3.f);
            unsigned short h = f2bf(v);
            tokh[ro + d] = h; tokl[ro + d] = f2bf(v - bf2f(h));
        }
        if (threadIdx.x == 0) tt[g] = lab_t[(size_t)n*T_ + t];
    } else {
        for (int d = threadIdx.x; d < D_; d += 256) {
            float v = uc[(size_t)b*D_ + d];
            unsigned short h = f2bf(v);
            tokh[ro + d] = h; tokl[ro + d] = f2bf(v - bf2f(h));
        }
        if (threadIdx.x == 0) tt[g] = 0.f;
    }
}

// convert+transpose weight K x N -> hi/lo planes [n][k]
__global__ void k_cvtw(const float* __restrict__ W,
                       unsigned short* __restrict__ th,
                       unsigned short* __restrict__ tl,
                       int Kd, int N) {
    int total = Kd * N;
    for (int id = blockIdx.x*256 + threadIdx.x; id < total; id += gridDim.x*256) {
        int n = id / Kd, k = id - n*Kd;
        float v = W[(size_t)k*N + n];
        unsigned short h = f2bf(v);
        th[id] = h; tl[id] = f2bf(v - bf2f(h));
    }
}

// split-bf16 MFMA GEMM from pre-converted planes.
// A: M x Kd (hi/lo), B(transposed): N x Kd (hi/lo), C: M x N fp32.
// BM=128, BN=64, BK=32; 256 threads / 4 waves, wave = 64x32 (4x2 frags)
template<bool ADD, bool BIAS, bool TRAIT>
__global__ __launch_bounds__(256) void k_mgemm(const unsigned short* __restrict__ ah,
                                               const unsigned short* __restrict__ al,
                                               const unsigned short* __restrict__ bh,
                                               const unsigned short* __restrict__ bl,
                                               const float* __restrict__ bias,
                                               const float* __restrict__ wtrait,
                                               const float* __restrict__ tt,
                                               float* __restrict__ C,
                                               int N, int Kd) {
    __shared__ unsigned short Ah[128*40], Al[128*40], Bh[64*40], Bl[64*40];
    int bn = blockIdx.x * 64;
    int bm = blockIdx.y * 128;
    int tid = threadIdx.x;
    int lane = tid & 63, wv = tid >> 6;
    int mbase = (wv >> 1)*64, nbase = (wv & 1)*32;
    int fr = lane & 15, kg = lane >> 4;
    floatx4 acc[4][2];
#pragma unroll
    for (int mi = 0; mi < 4; ++mi)
#pragma unroll
        for (int ni = 0; ni < 2; ++ni)
            acc[mi][ni] = (floatx4){0.f, 0.f, 0.f, 0.f};

    for (int k0 = 0; k0 < Kd; k0 += 32) {
#pragma unroll
        for (int f = 0; f < 2; ++f) {
            int v = f*256 + tid;
            int r = v >> 2, kq = v & 3;
            size_t g = (size_t)(bm + r)*Kd + k0 + kq*8;
            int off = r*40 + kq*8;
            *(int4*)(Ah + off) = *(const int4*)(ah + g);
            *(int4*)(Al + off) = *(const int4*)(al + g);
        }
        {
            int r = tid >> 2, kq = tid & 3;
            size_t g = (size_t)(bn + r)*Kd + k0 + kq*8;
            int off = r*40 + kq*8;
            *(int4*)(Bh + off) = *(const int4*)(bh + g);
            *(int4*)(Bl + off) = *(const int4*)(bl + g);
        }
        __syncthreads();

        bf16x8 bhf[2], blf[2];
#pragma unroll
        for (int ni = 0; ni < 2; ++ni) {
            int off = (nbase + ni*16 + fr)*40 + kg*8;
            bhf[ni] = *(const bf16x8*)(Bh + off);
            blf[ni] = *(const bf16x8*)(Bl + off);
        }
#pragma unroll
        for (int mi = 0; mi < 4; ++mi) {
            int off = (mbase + mi*16 + fr)*40 + kg*8;
            bf16x8 ahf = *(const bf16x8*)(Ah + off);
            bf16x8 alf = *(const bf16x8*)(Al + off);
#pragma unroll
            for (int ni = 0; ni < 2; ++ni) {
                floatx4 c = acc[mi][ni];
                c = __builtin_amdgcn_mfma_f32_16x16x32_bf16(ahf, bhf[ni], c, 0, 0, 0);
                c = __builtin_amdgcn_mfma_f32_16x16x32_bf16(alf, bhf[ni], c, 0, 0, 0);
                c = __builtin_amdgcn_mfma_f32_16x16x32_bf16(ahf, blf[ni], c, 0, 0, 0);
                acc[mi][ni] = c;
            }
        }
        __syncthreads();
    }
#pragma unroll
    for (int mi = 0; mi < 4; ++mi) {
        int m0 = bm + mbase + mi*16 + kg*4;
#pragma unroll
        for (int ni = 0; ni < 2; ++ni) {
            int n = bn + nbase + ni*16 + fr;
#pragma unroll
            for (int r = 0; r < 4; ++r) {
                float v = acc[mi][ni][r];
                if (TRAIT) v += tt[m0 + r] * wtrait[n];
                if (BIAS)  v += bias[n];
                size_t o = (size_t)(m0 + r)*N + n;
                if (ADD) C[o] += v; else C[o] = v;
            }
        }
    }
}

// layer norm -> fp32 out + bf16 hi/lo planes
__global__ __launch_bounds__(256) void k_ln(const float* __restrict__ x,
                                            const float* __restrict__ g,
                                            const float* __restrict__ b,
                                            float* __restrict__ xn,
                                            unsigned short* __restrict__ xnh,
                                            unsigned short* __restrict__ xnl) {
    int row = blockIdx.x, tid = threadIdx.x;
    float v = x[(size_t)row*H_ + tid];
    float mean = block_reduce_sum(v) * (1.f/H_);
    float d = v - mean;
    float var = block_reduce_sum(d*d) * (1.f/H_);
    float o = d * rsqrtf(var + 1e-5f) * g[tid] + b[tid];
    size_t oo = (size_t)row*H_ + tid;
    xn[oo] = o;
    unsigned short h = f2bf(o);
    xnh[oo] = h; xnl[oo] = f2bf(o - bf2f(h));
}

// fused mamba inner chain: conv+silu -> dbl (MFMA) -> dt -> selective scan -> gate.
// block = one sequence (n), 512 threads = one per d channel.
// LDS: xc [9][516] (padded), dbl [9][48].  Wx^T pre-converted to bf16 hi/lo planes.
__global__ __launch_bounds__(512) void k_mamba(const float* __restrict__ xz,
                                               const float* __restrict__ cw,
                                               const float* __restrict__ cb,
                                               const unsigned short* __restrict__ wxh,
                                               const unsigned short* __restrict__ wxl,
                                               const float* __restrict__ Wdt,
                                               const float* __restrict__ bdt,
                                               const float* __restrict__ A_log,
                                               const float* __restrict__ Dp,
                                               unsigned short* __restrict__ yh,
                                               unsigned short* __restrict__ yl) {
    __shared__ float xcS[L_][516];
    __shared__ float dblS[L_][48];
    int n = blockIdx.x, d = threadIdx.x;

    // ---- causal conv (KC=4) + silu; keep xc and z in registers ----
    float c0 = cw[d*4+0], c1 = cw[d*4+1], c2 = cw[d*4+2], c3 = cw[d*4+3];
    float bb = cb[d];
    const float* src = xz + (size_t)n*L_*(2*DI_) + d;
    float xc[L_], z[L_];
    float x0 = 0.f, x1 = 0.f, x2 = 0.f;
#pragma unroll
    for (int l = 0; l < L_; ++l) {
        float x3 = src[l*(2*DI_)];
        z[l]     = src[l*(2*DI_) + DI_];
        float s = bb + c0*x0 + c1*x1 + c2*x2 + c3*x3;
        float v = siluf_(s);
        xc[l] = v; xcS[l][d] = v;
        x0 = x1; x1 = x2; x2 = x3;
    }
    __syncthreads();

    // ---- dbl = xc(9x512) @ Wx(512x48) via split-bf16 MFMA on waves 0..2 ----
    int wv = d >> 6, lane = d & 63;
    if (wv < 3) {
        int fr = lane & 15, kg = lane >> 4;
        const unsigned short* bph = wxh + (size_t)(wv*16 + fr)*DI_;
        const unsigned short* bpl = wxl + (size_t)(wv*16 + fr)*DI_;
        floatx4 c = (floatx4){0.f, 0.f, 0.f, 0.f};
        for (int k0 = 0; k0 < DI_; k0 += 32) {
            int kb = k0 + kg*8;
            float av[8];
            if (fr < L_) {
                float4 q0 = *(const float4*)(&xcS[fr][kb]);
                float4 q1 = *(const float4*)(&xcS[fr][kb+4]);
                av[0]=q0.x; av[1]=q0.y; av[2]=q0.z; av[3]=q0.w;
                av[4]=q1.x; av[5]=q1.y; av[6]=q1.z; av[7]=q1.w;
            } else {
#pragma unroll
                for (int j = 0; j < 8; ++j) av[j] = 0.f;
            }
            bf16x8 ah, al;
#pragma unroll
            for (int j = 0; j < 8; ++j) {
                unsigned short hh = f2bf(av[j]);
                ah[j] = (short)hh;
                al[j] = (short)f2bf(av[j] - bf2f(hh));
            }
            bf16x8 bhf = *(const bf16x8*)(bph + kb);
            bf16x8 blf = *(const bf16x8*)(bpl + kb);
            c = __builtin_amdgcn_mfma_f32_16x16x32_bf16(ah, bhf, c, 0, 0, 0);
            c = __builtin_amdgcn_mfma_f32_16x16x32_bf16(al, bhf, c, 0, 0, 0);
            c = __builtin_amdgcn_mfma_f32_16x16x32_bf16(ah, blf, c, 0, 0, 0);
        }
#pragma unroll
        for (int r = 0; r < 4; ++r) {
            int row = kg*4 + r;
            if (row < L_) dblS[row][wv*16 + fr] = c[r];
        }
    }
    __syncthreads();

    // ---- dt + selective scan + gate, per-thread channel d ----
    float a[S_], wdt[R_];
#pragma unroll
    for (int s = 0; s < S_; ++s) a[s] = -expf(A_log[(size_t)d*S_ + s]);
#pragma unroll
    for (int r = 0; r < R_; ++r) wdt[r] = Wdt[(size_t)r*DI_ + d];
    float bdtv = bdt[d], dp = Dp[d];
    float h[S_];
#pragma unroll
    for (int s = 0; s < S_; ++s) h[s] = 0.f;
    size_t ob = (size_t)n*L_*DI_ + d;
#pragma unroll
    for (int l = 0; l < L_; ++l) {
        float s = bdtv;
#pragma unroll
        for (int r = 0; r < R_; ++r) s = fmaf(dblS[l][r], wdt[r], s);
        float dtv = softplusf_(s);
        float xcv = xc[l];
        float accv = 0.f;
#pragma unroll
        for (int si = 0; si < S_; ++si) {
            float Bv = dblS[l][16 + si], Cv = dblS[l][32 + si];
            h[si] = expf(dtv*a[si])*h[si] + dtv*Bv*xcv;
            accv = fmaf(h[si], Cv, accv);
        }
        float yv = (accv + dp*xcv) * siluf_(z[l]);
        unsigned short hh = f2bf(yv);
        yh[ob + (size_t)l*DI_] = hh;
        yl[ob + (size_t)l*DI_] = f2bf(yv - bf2f(hh));
    }
}

// head
__global__ __launch_bounds__(128) void k_head(const float* __restrict__ x,
                                              const float* __restrict__ W1,
                                              const float* __restrict__ b1,
                                              const float* __restrict__ W2,
                                              const float* __restrict__ b2,
                                              float* __restrict__ out) {
    int n = blockIdx.x, tid = threadIdx.x;
    __shared__ float ms[H_];
    const float* src = x + ((size_t)n*L_ + (L_-1))*H_;
    ms[tid] = src[tid];
    ms[tid+128] = src[tid+128];
    __syncthreads();
    float s = b1[tid];
#pragma unroll 8
    for (int k = 0; k < H_; ++k) s = fmaf(ms[k], W1[(size_t)k*128 + tid], s);
    float h = fmaxf(s, 0.f);
    float p = h * W2[tid];
    float tot = block_reduce_sum(p);
    if (tid == 0) out[n] = tot + b2[0];
}

// ---------------- launch ----------------

extern "C" void kernel_launch(void* const* d_in, const int* in_sizes, int n_in,
                              void* d_out, int out_size, void* d_ws, size_t ws_size,
                              hipStream_t stream) {
    const float* unl   = (const float*)d_in[0];
    const float* lab_e = (const float*)d_in[1];
    const float* lab_t = (const float*)d_in[2];
    const float* mlog  = (const float*)d_in[3];
    const float* Wp    = (const float*)d_in[4];
    const float* bp    = (const float*)d_in[5];
    const float* ln_g  = (const float*)d_in[6];
    const float* ln_b  = (const float*)d_in[7];
    const float* Win   = (const float*)d_in[8];
    const float* conv_w= (const float*)d_in[9];
    const float* conv_b= (const float*)d_in[10];
    const float* Wx    = (const float*)d_in[11];
    const float* Wdt   = (const float*)d_in[12];
    const float* bdt   = (const float*)d_in[13];
    const float* A_log = (const float*)d_in[14];
    const float* Dp    = (const float*)d_in[15];
    const float* Wout  = (const float*)d_in[16];
    const float* W1    = (const float*)d_in[17];
    const float* b1    = (const float*)d_in[18];
    const float* W2    = (const float*)d_in[19];
    const float* b2    = (const float*)d_in[20];

    float* ws = (float*)d_ws;
    // fixed layout (float units); ushort buffers cast from 4-aligned float offsets
    float* w    = ws + 0;                                    // 16
    int*   idx  = (int*)(ws + 16);                           // 10240 ints
    float* uc   = ws + 10256;                                // 196,608
    // old rn slot (100,000 floats) repurposed for Wx^T bf16 planes (4 layers)
    unsigned short* wxth = (unsigned short*)(ws + 206864);   // 98,304 ush = 49,152 f
    unsigned short* wxtl = (unsigned short*)(ws + 256016);   // 98,304 ush
    float* tt   = ws + 306864;                               // 11,520
    unsigned short* qnh   = (unsigned short*)(ws + 318384);  // 983,040 ush
    unsigned short* qnl   = (unsigned short*)(ws + 809904);
    unsigned short* wph   = (unsigned short*)(ws + 1301424); // 196,608 ush
    unsigned short* wpl   = (unsigned short*)(ws + 1399728);
    unsigned short* winh  = (unsigned short*)(ws + 1498032); // 1,048,576 ush
    unsigned short* winl  = (unsigned short*)(ws + 2022320);
    unsigned short* wouth = (unsigned short*)(ws + 2546608); // 524,288 ush
    unsigned short* woutl = (unsigned short*)(ws + 2808752);
    float* xa   = ws + 3070896;                              // 2,949,120
    float* xb   = ws + 6020016;                              // 2,949,120
    unsigned short* xnh   = (unsigned short*)(ws + 8969136); // 2,949,120 ush
    unsigned short* xnl   = (unsigned short*)(ws + 10443696);
    float* simreg = ws + 18369456;                           // 25,600,000
    float* sim  = simreg;
    float* xz   = simreg;                                    // 11,796,480 (phase 2)
    unsigned short* tokh = (unsigned short*)(simreg + 11796480); // 8,847,360 ush (dead before xz phase-2 grows)
    unsigned short* tokl = (unsigned short*)(simreg + 16220160);
    unsigned short* yh   = (unsigned short*)(simreg + 17694720); // 5,898,240 ush
    unsigned short* yl   = (unsigned short*)(simreg + 20643840);

    k_softmax_w<<<1, 64, 0, stream>>>(mlog, w);
    k_qn_uc<<<B_, 256, 0, stream>>>(unl, w, qnh, qnl, uc);
    // weight conversions (once per call)
    k_cvtw<<<(768*256 + 255)/256, 256, 0, stream>>>(Wp, wph, wpl, 768, 256);
    for (int i = 0; i < NL_; ++i) {
        k_cvtw<<<(256*1024 + 255)/256, 256, 0, stream>>>(Win + (size_t)i*H_*(2*DI_),
                                                         winh + (size_t)i*H_*(2*DI_),
                                                         winl + (size_t)i*H_*(2*DI_), 256, 1024);
        k_cvtw<<<(512*256 + 255)/256, 256, 0, stream>>>(Wout + (size_t)i*DI_*H_,
                                                        wouth + (size_t)i*DI_*H_,
                                                        woutl + (size_t)i*DI_*H_, 512, 256);
        k_cvtw<<<(512*48 + 255)/256, 256, 0, stream>>>(Wx + (size_t)i*DI_*48,
                                                       wxth + (size_t)i*48*DI_,
                                                       wxtl + (size_t)i*48*DI_, 512, 48);
    }
    k_simf<<<800, 512, 0, stream>>>(qnh, qnl, lab_e, w, sim);
    {
        dim3 g(B_, T_);
        k_topk<<<g, 256, 0, stream>>>(sim, idx);
    }
    k_toks<<<NROW, 256, 0, stream>>>(lab_e, lab_t, uc, idx, tokh, tokl, tt);
    {
        dim3 g(H_/64, NROW/128);
        k_mgemm<false,true,true><<<g, 256, 0, stream>>>(tokh, tokl, wph, wpl,
                                                        bp, Wp + (size_t)768*H_, tt, xa, H_, D_);
    }
    float* cur = xa;
    float* oth = xb;
    for (int i = 0; i < NL_; ++i) {
        k_ln<<<NROW, 256, 0, stream>>>(cur, ln_g + (size_t)i*H_, ln_b + (size_t)i*H_, oth, xnh, xnl);
        {
            dim3 g((2*DI_)/64, NROW/128);
            k_mgemm<false,false,false><<<g, 256, 0, stream>>>(xnh, xnl,
                winh + (size_t)i*H_*(2*DI_), winl + (size_t)i*H_*(2*DI_),
                nullptr, nullptr, nullptr, xz, 2*DI_, H_);
        }
        k_mamba<<<NBT, 512, 0, stream>>>(xz,
                                         conv_w + (size_t)i*DI_*KC_, conv_b + (size_t)i*DI_,
                                         wxth + (size_t)i*48*DI_, wxtl + (size_t)i*48*DI_,
                                         Wdt + (size_t)i*R_*DI_, bdt + (size_t)i*DI_,
                                         A_log + (size_t)i*DI_*S_, Dp + (size_t)i*DI_,
                                         yh, yl);
        {
            dim3 g(H_/64, NROW/128);
            k_mgemm<true,false,false><<<g, 256, 0, stream>>>(yh, yl,
                wouth + (size_t)i*DI_*H_, woutl + (size_t)i*DI_*H_,
                nullptr, nullptr, nullptr, oth, H_, DI_);
        }
        float* tmp = cur; cur = oth; oth = tmp;
    }
    k_head<<<NBT, 128, 0, stream>>>(cur, W1, b1, W2, b2, (float*)d_out);
}

// Round 3
// 1542.588 us; speedup vs baseline: 1.2394x; 1.2394x over previous
//
#include <hip/hip_runtime.h>
#include <math.h>

#define B_   256
#define NLAB 20000
#define M_   3
#define D_   768
#define T_   5
#define K_   8
#define H_   256
#define DI_  512
#define S_   16
#define R_   16
#define NL_  4
#define KC_  4
#define L_   9          // K+1 tokens
#define NBT  1280       // B*T sequences
#define NROW 11520      // NBT*L flattened rows

typedef __attribute__((ext_vector_type(8))) short bf16x8;
typedef __attribute__((ext_vector_type(4))) float floatx4;

// ---------------- helpers ----------------

__device__ __forceinline__ float block_reduce_sum(float v) {
    __shared__ float red[4];
    int lane = threadIdx.x & 63;
    int wid  = threadIdx.x >> 6;
#pragma unroll
    for (int o = 32; o > 0; o >>= 1) v += __shfl_down(v, o);
    if (lane == 0) red[wid] = v;
    __syncthreads();
    int nw = (int)(blockDim.x >> 6);
    float r = 0.f;
#pragma unroll
    for (int i = 0; i < 4; ++i) if (i < nw) r += red[i];
    __syncthreads();
    return r;
}

__device__ __forceinline__ float sigmoidf_(float x) { return 1.f / (1.f + expf(-x)); }
__device__ __forceinline__ float siluf_(float x)    { return x * sigmoidf_(x); }
__device__ __forceinline__ float softplusf_(float x){ return x > 20.f ? x : log1pf(expf(x)); }

// round-to-nearest-even fp32 -> bf16 bits
__device__ __forceinline__ unsigned short f2bf(float x) {
    unsigned u = __float_as_uint(x);
    unsigned r = (u + 0x7fffu + ((u >> 16) & 1u)) >> 16;
    return (unsigned short)r;
}
__device__ __forceinline__ float bf2f(unsigned short h) {
    return __uint_as_float(((unsigned)h) << 16);
}

// barrier that does NOT drain vmcnt: LDS ordering only.  Global register loads
// issued before this stay in flight across the barrier (T3/T4 counted-wait).
__device__ __forceinline__ void barrier_lds_only() {
    asm volatile("s_waitcnt lgkmcnt(0)" ::: "memory");
    __builtin_amdgcn_s_barrier();
}

// ---------------- kernels ----------------

__global__ void k_softmax_w(const float* __restrict__ mlog, float* __restrict__ w) {
    int t = threadIdx.x;
    if (t < T_) {
        float a = mlog[t*M_+0], b = mlog[t*M_+1], c = mlog[t*M_+2];
        float mx = fmaxf(a, fmaxf(b, c));
        float ea = expf(a-mx), eb = expf(b-mx), ec = expf(c-mx);
        float s = ea + eb + ec;
        w[t*M_+0] = ea/s; w[t*M_+1] = eb/s; w[t*M_+2] = ec/s;
    }
}

// qn (normalized queries) -> bf16 hi/lo planes ; uc = mean over m
__global__ __launch_bounds__(256) void k_qn_uc(const float* __restrict__ unl,
                                               const float* __restrict__ w,
                                               unsigned short* __restrict__ qnh,
                                               unsigned short* __restrict__ qnl,
                                               float* __restrict__ uc) {
    int b = blockIdx.x, tid = threadIdx.x;
    float e[3][3];
#pragma unroll
    for (int c = 0; c < 3; ++c) {
        int d = tid + c*256;
#pragma unroll
        for (int m = 0; m < 3; ++m)
            e[c][m] = unl[((size_t)b*3 + m)*D_ + d];
    }
#pragma unroll
    for (int c = 0; c < 3; ++c)
        uc[(size_t)b*D_ + tid + c*256] = (e[c][0] + e[c][1] + e[c][2]) * (1.f/3.f);
    for (int t = 0; t < T_; ++t) {
        float w0 = w[t*3+0], w1 = w[t*3+1], w2 = w[t*3+2];
        float q[3]; float ss = 0.f;
#pragma unroll
        for (int c = 0; c < 3; ++c) {
            q[c] = w0*e[c][0] + w1*e[c][1] + w2*e[c][2];
            ss += q[c]*q[c];
        }
        float tot = block_reduce_sum(ss);
        float inv = rsqrtf(tot + 1e-8f);
#pragma unroll
        for (int c = 0; c < 3; ++c) {
            float v = q[c]*inv;
            size_t o = ((size_t)t*B_ + b)*D_ + tid + c*256;
            unsigned short h = f2bf(v);
            qnh[o] = h; qnl[o] = f2bf(v - bf2f(h));
        }
    }
}

// weight+ssq+split-bf16 convert of one staged row chunk, store to LDS
__device__ __forceinline__ void cvt_store4(const float4* rb, float w0, float w1, float w2,
                                           unsigned short* bh, unsigned short* bl,
                                           int off, float& ss) {
    float4 s;
    s.x = w0*rb[0].x + w1*rb[1].x + w2*rb[2].x;
    s.y = w0*rb[0].y + w1*rb[1].y + w2*rb[2].y;
    s.z = w0*rb[0].z + w1*rb[1].z + w2*rb[2].z;
    s.w = w0*rb[0].w + w1*rb[1].w + w2*rb[2].w;
    ss += s.x*s.x + s.y*s.y + s.z*s.z + s.w*s.w;
    ushort4 h, l;
    h.x = f2bf(s.x); l.x = f2bf(s.x - bf2f(h.x));
    h.y = f2bf(s.y); l.y = f2bf(s.y - bf2f(h.y));
    h.z = f2bf(s.z); l.z = f2bf(s.z - bf2f(h.z));
    h.w = f2bf(s.w); l.w = f2bf(s.w - bf2f(h.w));
    *(ushort4*)(bh + off) = h;
    *(ushort4*)(bl + off) = l;
}

// split-bf16 MFMA sim GEMM, BM=256 (all b), BN=64, BK=32; 512 threads / 8 waves
// arranged 4m x 2n, wave tile 64x32 -> acc[4][2]=32 VGPR, total live ~110 VGPR
// so __launch_bounds__(512,4) (VGPR cap 128) holds WITHOUT spilling (round-2's
// 1.08 GB scratch-spill WRITE_SIZE was the regression).
// - A fragments read directly from global (qn planes, L2-hot), issued BEFORE the
//   rb prefetch so MFMA's vmcnt wait retires at vmcnt(3), leaving rb in flight
// - B staged in ping-pong LDS (2 x 10 KB); ONE lgkmcnt-only barrier per K-tile
// - XCD-swizzled 1-D grid, t innermost: 5 consecutive same-XCD blocks share a
//   0.59 MB lab_e chunk -> L2 reuse
// - row norms fused: ssq of weighted rows + 8-lane shfl reduce
__global__ __launch_bounds__(512, 4) void k_simf(const unsigned short* __restrict__ qnh,
                                                 const unsigned short* __restrict__ qnl,
                                                 const float* __restrict__ lab_e,
                                                 const float* __restrict__ w,
                                                 float* __restrict__ sim) {
    __shared__ unsigned short Bh[2*64*40], Bl[2*64*40];
    __shared__ float rnl[64];
    // 313 bn-chunks of 64 rows split across 8 XCDs (xcd0: 40, rest: 39), t innermost
    int bid = blockIdx.x;
    int xcd = bid & 7, s = bid >> 3;
    int cnt = (xcd == 0) ? 40 : 39;
    if (s >= cnt * 5) return;
    int start = (xcd == 0) ? 0 : 40 + (xcd - 1) * 39;
    int bnc = start + s / 5;
    int t = s - (s / 5) * 5;
    int bn = bnc * 64;

    float w0 = w[t*3+0], w1 = w[t*3+1], w2 = w[t*3+2];
    int tid = threadIdx.x;
    int lane = tid & 63, wv = tid >> 6;
    int mbase = (wv >> 1)*64, nbase = (wv & 1)*32;
    int fr = lane & 15, kg = lane >> 4;

    // B staging role: one row per thread (r), 4-col chunk kq
    int r = tid >> 3, kq = tid & 7;
    int gn = bn + r;
    bool vld = gn < NLAB;
    const float* bp = lab_e + (size_t)gn*(3*D_) + kq*4;
    int soff = r*40 + kq*4;

    floatx4 acc[4][2];
#pragma unroll
    for (int mi = 0; mi < 4; ++mi)
#pragma unroll
        for (int ni = 0; ni < 2; ++ni)
            acc[mi][ni] = (floatx4){0.f, 0.f, 0.f, 0.f};

    float ss = 0.f;
    float4 rb[3];
    float4 z4 = make_float4(0.f, 0.f, 0.f, 0.f);
    rb[0] = rb[1] = rb[2] = z4;
    if (vld) { rb[0] = *(const float4*)(bp);
               rb[1] = *(const float4*)(bp + D_);
               rb[2] = *(const float4*)(bp + 2*D_); }
    // prologue: convert tile 0 into buffer 0
    cvt_store4(rb, w0, w1, w2, Bh, Bl, soff, ss);

    const unsigned short* aph = qnh + ((size_t)t*B_ + mbase + fr)*D_ + kg*8;
    const unsigned short* apl = qnl + ((size_t)t*B_ + mbase + fr)*D_ + kg*8;

    for (int kt = 0; kt < 24; ++kt) {
        int cur = kt & 1;
        const unsigned short* bhr = Bh + cur*2560;
        const unsigned short* blr = Bl + cur*2560;
        unsigned short* bhw = Bh + (cur^1)*2560;
        unsigned short* blw = Bl + (cur^1)*2560;
        int k0 = kt*32;

        // A fragment loads for THIS tile — issued first so the MFMA's vmcnt
        // wait retires without draining the rb prefetch behind it
        bf16x8 ahf[4], alf[4];
#pragma unroll
        for (int mi = 0; mi < 4; ++mi) {
            ahf[mi] = *(const bf16x8*)(aph + (size_t)mi*16*D_ + k0);
            alf[mi] = *(const bf16x8*)(apl + (size_t)mi*16*D_ + k0);
        }
        // raw-B register prefetch for tile kt+1 — flies across the barrier
        if (kt < 23) {
            const float* p = bp + k0 + 32;
            if (vld) { rb[0] = *(const float4*)(p);
                       rb[1] = *(const float4*)(p + D_);
                       rb[2] = *(const float4*)(p + 2*D_); }
        }

        barrier_lds_only();        // buf[cur] writes (prev iter) now visible

        bf16x8 bhf[2], blf[2];
#pragma unroll
        for (int ni = 0; ni < 2; ++ni) {
            int off = (nbase + ni*16 + fr)*40 + kg*8;
            bhf[ni] = *(const bf16x8*)(bhr + off);
            blf[ni] = *(const bf16x8*)(blr + off);
        }
#pragma unroll
        for (int mi = 0; mi < 4; ++mi) {
#pragma unroll
            for (int ni = 0; ni < 2; ++ni) {
                floatx4 c = acc[mi][ni];
                c = __builtin_amdgcn_mfma_f32_16x16x32_bf16(ahf[mi], bhf[ni], c, 0, 0, 0);
                c = __builtin_amdgcn_mfma_f32_16x16x32_bf16(alf[mi], bhf[ni], c, 0, 0, 0);
                c = __builtin_amdgcn_mfma_f32_16x16x32_bf16(ahf[mi], blf[ni], c, 0, 0, 0);
                acc[mi][ni] = c;
            }
        }
        // convert tile kt+1 into the other buffer (read next iter, after barrier)
        if (kt < 23)
            cvt_store4(rb, w0, w1, w2, bhw, blw, soff, ss);
    }

    // fold rn: reduce ssq across the 8 threads of each row
    float t0 = ss;
#pragma unroll
    for (int m = 1; m <= 4; m <<= 1) t0 += __shfl_xor(t0, m);
    if ((tid & 7) == 0) rnl[tid >> 3] = rsqrtf(t0 + 1e-8f);
    __syncthreads();

    float* st = sim + (size_t)t*B_*NLAB;
#pragma unroll
    for (int mi = 0; mi < 4; ++mi) {
        int m = mbase + mi*16 + kg*4;
#pragma unroll
        for (int ni = 0; ni < 2; ++ni) {
            int nl = nbase + ni*16 + fr;
            int n = bn + nl;
            if (n < NLAB) {
                float rv = rnl[nl];
#pragma unroll
                for (int r2 = 0; r2 < 4; ++r2)
                    st[(size_t)(m + r2)*NLAB + n] = acc[mi][ni][r2] * rv;
            }
        }
    }
}

// per-row top-8, grid (B, T)
__global__ __launch_bounds__(256) void k_topk(const float* __restrict__ sim,
                                              int* __restrict__ idx_out) {
    int b = blockIdx.x;
    int t = blockIdx.y;
    int tid = threadIdx.x;
    const float* row = sim + ((size_t)t*B_ + b)*NLAB;
    float tv[8]; int ti[8];
#pragma unroll
    for (int k = 0; k < 8; ++k) { tv[k] = -3e38f; ti[k] = 0x7fffffff; }
    for (int n = tid; n < NLAB; n += 256) {
        float v = row[n];
        if (v > tv[7]) {
            tv[7] = v; ti[7] = n;
#pragma unroll
            for (int k = 7; k > 0; --k) {
                if (tv[k] > tv[k-1]) {
                    float fv = tv[k]; tv[k] = tv[k-1]; tv[k-1] = fv;
                    int fi = ti[k]; ti[k] = ti[k-1]; ti[k-1] = fi;
                }
            }
        }
    }
    __shared__ float sv[2048];
    __shared__ int   si[2048];
    __shared__ float pv[256];
    __shared__ int   pi[256];
    __shared__ int   pp[256];
#pragma unroll
    for (int k = 0; k < 8; ++k) { sv[tid*8+k] = tv[k]; si[tid*8+k] = ti[k]; }
    __syncthreads();
    for (int r = 0; r < 8; ++r) {
        float bv = -3e38f; int bi = 0x7fffffff; int bp = 0;
#pragma unroll
        for (int k = 0; k < 8; ++k) {
            int p = tid*8 + k;
            float v = sv[p]; int ii = si[p];
            if (v > bv || (v == bv && ii < bi)) { bv = v; bi = ii; bp = p; }
        }
        pv[tid] = bv; pi[tid] = bi; pp[tid] = bp;
        __syncthreads();
        for (int off = 128; off > 0; off >>= 1) {
            if (tid < off) {
                if (pv[tid+off] > pv[tid] || (pv[tid+off] == pv[tid] && pi[tid+off] < pi[tid])) {
                    pv[tid] = pv[tid+off]; pi[tid] = pi[tid+off]; pp[tid] = pp[tid+off];
                }
            }
            __syncthreads();
        }
        if (tid == 0) {
            idx_out[((size_t)b*T_ + t)*K_ + r] = pi[0];
            sv[pp[0]] = -3e38f;
        }
        __syncthreads();
    }
}

// build token planes (bf16 hi/lo, 768 cols) + trait vector tt
__global__ __launch_bounds__(256) void k_toks(const float* __restrict__ lab_e,
                                              const float* __restrict__ lab_t,
                                              const float* __restrict__ uc,
                                              const int* __restrict__ idx,
                                              unsigned short* __restrict__ tokh,
                                              unsigned short* __restrict__ tokl,
                                              float* __restrict__ tt) {
    int g = blockIdx.x;            // 0..NROW-1
    int bt = g / L_, l = g % L_;
    int b = bt / T_, t = bt % T_;
    size_t ro = (size_t)g*D_;
    if (l < K_) {
        int n = idx[(size_t)bt*K_ + l];
        for (int d = threadIdx.x; d < D_; d += 256) {
            size_t base = (size_t)n*(3*D_) + d;
            float v = (lab_e[base] + lab_e[base + D_] + lab_e[base + 2*D_]) * (1.f/3.f);
            unsigned short h = f2bf(v);
            tokh[ro + d] = h; tokl[ro + d] = f2bf(v - bf2f(h));
        }
        if (threadIdx.x == 0) tt[g] = lab_t[(size_t)n*T_ + t];
    } else {
        for (int d = threadIdx.x; d < D_; d += 256) {
            float v = uc[(size_t)b*D_ + d];
            unsigned short h = f2bf(v);
            tokh[ro + d] = h; tokl[ro + d] = f2bf(v - bf2f(h));
        }
        if (threadIdx.x == 0) tt[g] = 0.f;
    }
}

// convert+transpose weight K x N -> hi/lo planes [n][k]
__global__ void k_cvtw(const float* __restrict__ W,
                       unsigned short* __restrict__ th,
                       unsigned short* __restrict__ tl,
                       int Kd, int N) {
    int total = Kd * N;
    for (int id = blockIdx.x*256 + threadIdx.x; id < total; id += gridDim.x*256) {
        int n = id / Kd, k = id - n*Kd;
        float v = W[(size_t)k*N + n];
        unsigned short h = f2bf(v);
        th[id] = h; tl[id] = f2bf(v - bf2f(h));
    }
}

// split-bf16 MFMA GEMM from pre-converted planes.
// A: M x Kd (hi/lo), B(transposed): N x Kd (hi/lo), C: M x N fp32.
// BM=128, BN=64, BK=32; 256 threads / 4 waves, wave = 64x32 (4x2 frags)
template<bool ADD, bool BIAS, bool TRAIT>
__global__ __launch_bounds__(256) void k_mgemm(const unsigned short* __restrict__ ah,
                                               const unsigned short* __restrict__ al,
                                               const unsigned short* __restrict__ bh,
                                               const unsigned short* __restrict__ bl,
                                               const float* __restrict__ bias,
                                               const float* __restrict__ wtrait,
                                               const float* __restrict__ tt,
                                               float* __restrict__ C,
                                               int N, int Kd) {
    __shared__ unsigned short Ah[128*40], Al[128*40], Bh[64*40], Bl[64*40];
    int bn = blockIdx.x * 64;
    int bm = blockIdx.y * 128;
    int tid = threadIdx.x;
    int lane = tid & 63, wv = tid >> 6;
    int mbase = (wv >> 1)*64, nbase = (wv & 1)*32;
    int fr = lane & 15, kg = lane >> 4;
    floatx4 acc[4][2];
#pragma unroll
    for (int mi = 0; mi < 4; ++mi)
#pragma unroll
        for (int ni = 0; ni < 2; ++ni)
            acc[mi][ni] = (floatx4){0.f, 0.f, 0.f, 0.f};

    for (int k0 = 0; k0 < Kd; k0 += 32) {
#pragma unroll
        for (int f = 0; f < 2; ++f) {
            int v = f*256 + tid;
            int r = v >> 2, kq = v & 3;
            size_t g = (size_t)(bm + r)*Kd + k0 + kq*8;
            int off = r*40 + kq*8;
            *(int4*)(Ah + off) = *(const int4*)(ah + g);
            *(int4*)(Al + off) = *(const int4*)(al + g);
        }
        {
            int r = tid >> 2, kq = tid & 3;
            size_t g = (size_t)(bn + r)*Kd + k0 + kq*8;
            int off = r*40 + kq*8;
            *(int4*)(Bh + off) = *(const int4*)(bh + g);
            *(int4*)(Bl + off) = *(const int4*)(bl + g);
        }
        __syncthreads();

        bf16x8 bhf[2], blf[2];
#pragma unroll
        for (int ni = 0; ni < 2; ++ni) {
            int off = (nbase + ni*16 + fr)*40 + kg*8;
            bhf[ni] = *(const bf16x8*)(Bh + off);
            blf[ni] = *(const bf16x8*)(Bl + off);
        }
#pragma unroll
        for (int mi = 0; mi < 4; ++mi) {
            int off = (mbase + mi*16 + fr)*40 + kg*8;
            bf16x8 ahf = *(const bf16x8*)(Ah + off);
            bf16x8 alf = *(const bf16x8*)(Al + off);
#pragma unroll
            for (int ni = 0; ni < 2; ++ni) {
                floatx4 c = acc[mi][ni];
                c = __builtin_amdgcn_mfma_f32_16x16x32_bf16(ahf, bhf[ni], c, 0, 0, 0);
                c = __builtin_amdgcn_mfma_f32_16x16x32_bf16(alf, bhf[ni], c, 0, 0, 0);
                c = __builtin_amdgcn_mfma_f32_16x16x32_bf16(ahf, blf[ni], c, 0, 0, 0);
                acc[mi][ni] = c;
            }
        }
        __syncthreads();
    }
#pragma unroll
    for (int mi = 0; mi < 4; ++mi) {
        int m0 = bm + mbase + mi*16 + kg*4;
#pragma unroll
        for (int ni = 0; ni < 2; ++ni) {
            int n = bn + nbase + ni*16 + fr;
#pragma unroll
            for (int r = 0; r < 4; ++r) {
                float v = acc[mi][ni][r];
                if (TRAIT) v += tt[m0 + r] * wtrait[n];
                if (BIAS)  v += bias[n];
                size_t o = (size_t)(m0 + r)*N + n;
                if (ADD) C[o] += v; else C[o] = v;
            }
        }
    }
}

// layer norm -> fp32 out + bf16 hi/lo planes
__global__ __launch_bounds__(256) void k_ln(const float* __restrict__ x,
                                            const float* __restrict__ g,
                                            const float* __restrict__ b,
                                            float* __restrict__ xn,
                                            unsigned short* __restrict__ xnh,
                                            unsigned short* __restrict__ xnl) {
    int row = blockIdx.x, tid = threadIdx.x;
    float v = x[(size_t)row*H_ + tid];
    float mean = block_reduce_sum(v) * (1.f/H_);
    float d = v - mean;
    float var = block_reduce_sum(d*d) * (1.f/H_);
    float o = d * rsqrtf(var + 1e-5f) * g[tid] + b[tid];
    size_t oo = (size_t)row*H_ + tid;
    xn[oo] = o;
    unsigned short h = f2bf(o);
    xnh[oo] = h; xnl[oo] = f2bf(o - bf2f(h));
}

// fused mamba inner chain: conv+silu -> dbl (MFMA) -> dt -> selective scan -> gate.
// block = one sequence (n), 512 threads = one per d channel.
// LDS: xc [9][516] (padded), dbl [9][48].  Wx^T pre-converted to bf16 hi/lo planes.
__global__ __launch_bounds__(512) void k_mamba(const float* __restrict__ xz,
                                               const float* __restrict__ cw,
                                               const float* __restrict__ cb,
                                               const unsigned short* __restrict__ wxh,
                                               const unsigned short* __restrict__ wxl,
                                               const float* __restrict__ Wdt,
                                               const float* __restrict__ bdt,
                                               const float* __restrict__ A_log,
                                               const float* __restrict__ Dp,
                                               unsigned short* __restrict__ yh,
                                               unsigned short* __restrict__ yl) {
    __shared__ float xcS[L_][516];
    __shared__ float dblS[L_][48];
    int n = blockIdx.x, d = threadIdx.x;

    // ---- causal conv (KC=4) + silu; keep xc and z in registers ----
    float c0 = cw[d*4+0], c1 = cw[d*4+1], c2 = cw[d*4+2], c3 = cw[d*4+3];
    float bb = cb[d];
    const float* src = xz + (size_t)n*L_*(2*DI_) + d;
    float xc[L_], z[L_];
    float x0 = 0.f, x1 = 0.f, x2 = 0.f;
#pragma unroll
    for (int l = 0; l < L_; ++l) {
        float x3 = src[l*(2*DI_)];
        z[l]     = src[l*(2*DI_) + DI_];
        float s = bb + c0*x0 + c1*x1 + c2*x2 + c3*x3;
        float v = siluf_(s);
        xc[l] = v; xcS[l][d] = v;
        x0 = x1; x1 = x2; x2 = x3;
    }
    __syncthreads();

    // ---- dbl = xc(9x512) @ Wx(512x48) via split-bf16 MFMA on waves 0..2 ----
    int wv = d >> 6, lane = d & 63;
    if (wv < 3) {
        int fr = lane & 15, kg = lane >> 4;
        const unsigned short* bph = wxh + (size_t)(wv*16 + fr)*DI_;
        const unsigned short* bpl = wxl + (size_t)(wv*16 + fr)*DI_;
        floatx4 c = (floatx4){0.f, 0.f, 0.f, 0.f};
        for (int k0 = 0; k0 < DI_; k0 += 32) {
            int kb = k0 + kg*8;
            float av[8];
            if (fr < L_) {
                float4 q0 = *(const float4*)(&xcS[fr][kb]);
                float4 q1 = *(const float4*)(&xcS[fr][kb+4]);
                av[0]=q0.x; av[1]=q0.y; av[2]=q0.z; av[3]=q0.w;
                av[4]=q1.x; av[5]=q1.y; av[6]=q1.z; av[7]=q1.w;
            } else {
#pragma unroll
                for (int j = 0; j < 8; ++j) av[j] = 0.f;
            }
            bf16x8 ah, al;
#pragma unroll
            for (int j = 0; j < 8; ++j) {
                unsigned short hh = f2bf(av[j]);
                ah[j] = (short)hh;
                al[j] = (short)f2bf(av[j] - bf2f(hh));
            }
            bf16x8 bhf = *(const bf16x8*)(bph + kb);
            bf16x8 blf = *(const bf16x8*)(bpl + kb);
            c = __builtin_amdgcn_mfma_f32_16x16x32_bf16(ah, bhf, c, 0, 0, 0);
            c = __builtin_amdgcn_mfma_f32_16x16x32_bf16(al, bhf, c, 0, 0, 0);
            c = __builtin_amdgcn_mfma_f32_16x16x32_bf16(ah, blf, c, 0, 0, 0);
        }
#pragma unroll
        for (int r = 0; r < 4; ++r) {
            int row = kg*4 + r;
            if (row < L_) dblS[row][wv*16 + fr] = c[r];
        }
    }
    __syncthreads();

    // ---- dt + selective scan + gate, per-thread channel d ----
    float a[S_], wdt[R_];
#pragma unroll
    for (int s = 0; s < S_; ++s) a[s] = -expf(A_log[(size_t)d*S_ + s]);
#pragma unroll
    for (int r = 0; r < R_; ++r) wdt[r] = Wdt[(size_t)r*DI_ + d];
    float bdtv = bdt[d], dp = Dp[d];
    float h[S_];
#pragma unroll
    for (int s = 0; s < S_; ++s) h[s] = 0.f;
    size_t ob = (size_t)n*L_*DI_ + d;
#pragma unroll
    for (int l = 0; l < L_; ++l) {
        float s = bdtv;
#pragma unroll
        for (int r = 0; r < R_; ++r) s = fmaf(dblS[l][r], wdt[r], s);
        float dtv = softplusf_(s);
        float xcv = xc[l];
        float accv = 0.f;
#pragma unroll
        for (int si = 0; si < S_; ++si) {
            float Bv = dblS[l][16 + si], Cv = dblS[l][32 + si];
            h[si] = expf(dtv*a[si])*h[si] + dtv*Bv*xcv;
            accv = fmaf(h[si], Cv, accv);
        }
        float yv = (accv + dp*xcv) * siluf_(z[l]);
        unsigned short hh = f2bf(yv);
        yh[ob + (size_t)l*DI_] = hh;
        yl[ob + (size_t)l*DI_] = f2bf(yv - bf2f(hh));
    }
}

// head
__global__ __launch_bounds__(128) void k_head(const float* __restrict__ x,
                                              const float* __restrict__ W1,
                                              const float* __restrict__ b1,
                                              const float* __restrict__ W2,
                                              const float* __restrict__ b2,
                                              float* __restrict__ out) {
    int n = blockIdx.x, tid = threadIdx.x;
    __shared__ float ms[H_];
    const float* src = x + ((size_t)n*L_ + (L_-1))*H_;
    ms[tid] = src[tid];
    ms[tid+128] = src[tid+128];
    __syncthreads();
    float s = b1[tid];
#pragma unroll 8
    for (int k = 0; k < H_; ++k) s = fmaf(ms[k], W1[(size_t)k*128 + tid], s);
    float h = fmaxf(s, 0.f);
    float p = h * W2[tid];
    float tot = block_reduce_sum(p);
    if (tid == 0) out[n] = tot + b2[0];
}

// ---------------- launch ----------------

extern "C" void kernel_launch(void* const* d_in, const int* in_sizes, int n_in,
                              void* d_out, int out_size, void* d_ws, size_t ws_size,
                              hipStream_t stream) {
    const float* unl   = (const float*)d_in[0];
    const float* lab_e = (const float*)d_in[1];
    const float* lab_t = (const float*)d_in[2];
    const float* mlog  = (const float*)d_in[3];
    const float* Wp    = (const float*)d_in[4];
    const float* bp    = (const float*)d_in[5];
    const float* ln_g  = (const float*)d_in[6];
    const float* ln_b  = (const float*)d_in[7];
    const float* Win   = (const float*)d_in[8];
    const float* conv_w= (const float*)d_in[9];
    const float* conv_b= (const float*)d_in[10];
    const float* Wx    = (const float*)d_in[11];
    const float* Wdt   = (const float*)d_in[12];
    const float* bdt   = (const float*)d_in[13];
    const float* A_log = (const float*)d_in[14];
    const float* Dp    = (const float*)d_in[15];
    const float* Wout  = (const float*)d_in[16];
    const float* W1    = (const float*)d_in[17];
    const float* b1    = (const float*)d_in[18];
    const float* W2    = (const float*)d_in[19];
    const float* b2    = (const float*)d_in[20];

    float* ws = (float*)d_ws;
    // fixed layout (float units); ushort buffers cast from 4-aligned float offsets
    float* w    = ws + 0;                                    // 16
    int*   idx  = (int*)(ws + 16);                           // 10240 ints
    float* uc   = ws + 10256;                                // 196,608
    // old rn slot (100,000 floats) repurposed for Wx^T bf16 planes (4 layers)
    unsigned short* wxth = (unsigned short*)(ws + 206864);   // 98,304 ush = 49,152 f
    unsigned short* wxtl = (unsigned short*)(ws + 256016);   // 98,304 ush
    float* tt   = ws + 306864;                               // 11,520
    unsigned short* qnh   = (unsigned short*)(ws + 318384);  // 983,040 ush
    unsigned short* qnl   = (unsigned short*)(ws + 809904);
    unsigned short* wph   = (unsigned short*)(ws + 1301424); // 196,608 ush
    unsigned short* wpl   = (unsigned short*)(ws + 1399728);
    unsigned short* winh  = (unsigned short*)(ws + 1498032); // 1,048,576 ush
    unsigned short* winl  = (unsigned short*)(ws + 2022320);
    unsigned short* wouth = (unsigned short*)(ws + 2546608); // 524,288 ush
    unsigned short* woutl = (unsigned short*)(ws + 2808752);
    float* xa   = ws + 3070896;                              // 2,949,120
    float* xb   = ws + 6020016;                              // 2,949,120
    unsigned short* xnh   = (unsigned short*)(ws + 8969136); // 2,949,120 ush
    unsigned short* xnl   = (unsigned short*)(ws + 10443696);
    float* simreg = ws + 18369456;                           // 25,600,000
    float* sim  = simreg;
    float* xz   = simreg;                                    // 11,796,480 (phase 2)
    unsigned short* tokh = (unsigned short*)(simreg + 11796480); // 8,847,360 ush (dead before xz phase-2 grows)
    unsigned short* tokl = (unsigned short*)(simreg + 16220160);
    unsigned short* yh   = (unsigned short*)(simreg + 17694720); // 5,898,240 ush
    unsigned short* yl   = (unsigned short*)(simreg + 20643840);

    k_softmax_w<<<1, 64, 0, stream>>>(mlog, w);
    k_qn_uc<<<B_, 256, 0, stream>>>(unl, w, qnh, qnl, uc);
    // weight conversions (once per call)
    k_cvtw<<<(768*256 + 255)/256, 256, 0, stream>>>(Wp, wph, wpl, 768, 256);
    for (int i = 0; i < NL_; ++i) {
        k_cvtw<<<(256*1024 + 255)/256, 256, 0, stream>>>(Win + (size_t)i*H_*(2*DI_),
                                                         winh + (size_t)i*H_*(2*DI_),
                                                         winl + (size_t)i*H_*(2*DI_), 256, 1024);
        k_cvtw<<<(512*256 + 255)/256, 256, 0, stream>>>(Wout + (size_t)i*DI_*H_,
                                                        wouth + (size_t)i*DI_*H_,
                                                        woutl + (size_t)i*DI_*H_, 512, 256);
        k_cvtw<<<(512*48 + 255)/256, 256, 0, stream>>>(Wx + (size_t)i*DI_*48,
                                                       wxth + (size_t)i*48*DI_,
                                                       wxtl + (size_t)i*48*DI_, 512, 48);
    }
    k_simf<<<1600, 512, 0, stream>>>(qnh, qnl, lab_e, w, sim);
    {
        dim3 g(B_, T_);
        k_topk<<<g, 256, 0, stream>>>(sim, idx);
    }
    k_toks<<<NROW, 256, 0, stream>>>(lab_e, lab_t, uc, idx, tokh, tokl, tt);
    {
        dim3 g(H_/64, NROW/128);
        k_mgemm<false,true,true><<<g, 256, 0, stream>>>(tokh, tokl, wph, wpl,
                                                        bp, Wp + (size_t)768*H_, tt, xa, H_, D_);
    }
    float* cur = xa;
    float* oth = xb;
    for (int i = 0; i < NL_; ++i) {
        k_ln<<<NROW, 256, 0, stream>>>(cur, ln_g + (size_t)i*H_, ln_b + (size_t)i*H_, oth, xnh, xnl);
        {
            dim3 g((2*DI_)/64, NROW/128);
            k_mgemm<false,false,false><<<g, 256, 0, stream>>>(xnh, xnl,
                winh + (size_t)i*H_*(2*DI_), winl + (size_t)i*H_*(2*DI_),
                nullptr, nullptr, nullptr, xz, 2*DI_, H_);
        }
        k_mamba<<<NBT, 512, 0, stream>>>(xz,
                                         conv_w + (size_t)i*DI_*KC_, conv_b + (size_t)i*DI_,
                                         wxth + (size_t)i*48*DI_, wxtl + (size_t)i*48*DI_,
                                         Wdt + (size_t)i*R_*DI_, bdt + (size_t)i*DI_,
                                         A_log + (size_t)i*DI_*S_, Dp + (size_t)i*DI_,
                                         yh, yl);
        {
            dim3 g(H_/64, NROW/128);
            k_mgemm<true,false,false><<<g, 256, 0, stream>>>(yh, yl,
                wouth + (size_t)i*DI_*H_, woutl + (size_t)i*DI_*H_,
                nullptr, nullptr, nullptr, oth, H_, DI_);
        }
        float* tmp = cur; cur = oth; oth = tmp;
    }
    k_head<<<NBT, 128, 0, stream>>>(cur, W1, b1, W2, b2, (float*)d_out);
}

// Round 4
// 1416.615 us; speedup vs baseline: 1.3496x; 1.0889x over previous
//
#include <hip/hip_runtime.h>
#include <math.h>

#define B_   256
#define NLAB 20000
#define M_   3
#define D_   768
#define T_   5
#define K_   8
#define H_   256
#define DI_  512
#define S_   16
#define R_   16
#define NL_  4
#define KC_  4
#define L_   9          // K+1 tokens
#define NBT  1280       // B*T sequences
#define NROW 11520      // NBT*L flattened rows

typedef __attribute__((ext_vector_type(8))) short bf16x8;
typedef __attribute__((ext_vector_type(4))) float floatx4;

// ---------------- helpers ----------------

__device__ __forceinline__ float block_reduce_sum(float v) {
    __shared__ float red[4];
    int lane = threadIdx.x & 63;
    int wid  = threadIdx.x >> 6;
#pragma unroll
    for (int o = 32; o > 0; o >>= 1) v += __shfl_down(v, o);
    if (lane == 0) red[wid] = v;
    __syncthreads();
    int nw = (int)(blockDim.x >> 6);
    float r = 0.f;
#pragma unroll
    for (int i = 0; i < 4; ++i) if (i < nw) r += red[i];
    __syncthreads();
    return r;
}

__device__ __forceinline__ float sigmoidf_(float x) { return 1.f / (1.f + expf(-x)); }
__device__ __forceinline__ float siluf_(float x)    { return x * sigmoidf_(x); }
__device__ __forceinline__ float softplusf_(float x){ return x > 20.f ? x : log1pf(expf(x)); }

// round-to-nearest-even fp32 -> bf16 bits
__device__ __forceinline__ unsigned short f2bf(float x) {
    unsigned u = __float_as_uint(x);
    unsigned r = (u + 0x7fffu + ((u >> 16) & 1u)) >> 16;
    return (unsigned short)r;
}
__device__ __forceinline__ float bf2f(unsigned short h) {
    return __uint_as_float(((unsigned)h) << 16);
}

// barrier that does NOT drain vmcnt: LDS ordering only.  Global register loads
// issued before this stay in flight across the barrier.
__device__ __forceinline__ void barrier_lds_only() {
    asm volatile("s_waitcnt lgkmcnt(0)" ::: "memory");
    __builtin_amdgcn_s_barrier();
}

// ---------------- kernels ----------------

__global__ void k_softmax_w(const float* __restrict__ mlog, float* __restrict__ w) {
    int t = threadIdx.x;
    if (t < T_) {
        float a = mlog[t*M_+0], b = mlog[t*M_+1], c = mlog[t*M_+2];
        float mx = fmaxf(a, fmaxf(b, c));
        float ea = expf(a-mx), eb = expf(b-mx), ec = expf(c-mx);
        float s = ea + eb + ec;
        w[t*M_+0] = ea/s; w[t*M_+1] = eb/s; w[t*M_+2] = ec/s;
    }
}

// qn (normalized queries) -> bf16 hi/lo planes ; uc = mean over m
__global__ __launch_bounds__(256) void k_qn_uc(const float* __restrict__ unl,
                                               const float* __restrict__ w,
                                               unsigned short* __restrict__ qnh,
                                               unsigned short* __restrict__ qnl,
                                               float* __restrict__ uc) {
    int b = blockIdx.x, tid = threadIdx.x;
    float e[3][3];
#pragma unroll
    for (int c = 0; c < 3; ++c) {
        int d = tid + c*256;
#pragma unroll
        for (int m = 0; m < 3; ++m)
            e[c][m] = unl[((size_t)b*3 + m)*D_ + d];
    }
#pragma unroll
    for (int c = 0; c < 3; ++c)
        uc[(size_t)b*D_ + tid + c*256] = (e[c][0] + e[c][1] + e[c][2]) * (1.f/3.f);
    for (int t = 0; t < T_; ++t) {
        float w0 = w[t*3+0], w1 = w[t*3+1], w2 = w[t*3+2];
        float q[3]; float ss = 0.f;
#pragma unroll
        for (int c = 0; c < 3; ++c) {
            q[c] = w0*e[c][0] + w1*e[c][1] + w2*e[c][2];
            ss += q[c]*q[c];
        }
        float tot = block_reduce_sum(ss);
        float inv = rsqrtf(tot + 1e-8f);
#pragma unroll
        for (int c = 0; c < 3; ++c) {
            float v = q[c]*inv;
            size_t o = ((size_t)t*B_ + b)*D_ + tid + c*256;
            unsigned short h = f2bf(v);
            qnh[o] = h; qnl[o] = f2bf(v - bf2f(h));
        }
    }
}

// weight+ssq+split-bf16 convert of one staged row chunk, store to LDS
__device__ __forceinline__ void cvt_store4(const float4* rb, float w0, float w1, float w2,
                                           unsigned short* bh, unsigned short* bl,
                                           int off, float& ss) {
    float4 s;
    s.x = w0*rb[0].x + w1*rb[1].x + w2*rb[2].x;
    s.y = w0*rb[0].y + w1*rb[1].y + w2*rb[2].y;
    s.z = w0*rb[0].z + w1*rb[1].z + w2*rb[2].z;
    s.w = w0*rb[0].w + w1*rb[1].w + w2*rb[2].w;
    ss += s.x*s.x + s.y*s.y + s.z*s.z + s.w*s.w;
    ushort4 h, l;
    h.x = f2bf(s.x); l.x = f2bf(s.x - bf2f(h.x));
    h.y = f2bf(s.y); l.y = f2bf(s.y - bf2f(h.y));
    h.z = f2bf(s.z); l.z = f2bf(s.z - bf2f(h.z));
    h.w = f2bf(s.w); l.w = f2bf(s.w - bf2f(h.w));
    *(ushort4*)(bh + off) = h;
    *(ushort4*)(bl + off) = l;
}

// split-bf16 MFMA sim GEMM.  BM=128, BN=128, BK=32; 512 threads / 8 waves
// (2m x 4n), wave tile 64x32 -> acc[4][2] = 32 VGPR.
// - A (qn planes) AND B (weighted lab_e) double-buffered in LDS, pad 36
//   (~74 KB -> 2 blocks/CU).  A staged via coalesced int4 copies: cuts the
//   round-3 per-wave global fragment gathers (2.4 GB of L3 traffic, the
//   latency bottleneck) down to 600 MB of coalesced staging.
// - ONE lgkm-only barrier per K-tile; next tile's global loads issued in the
//   tail so they stay in flight across the barrier and the MFMA phase.
// - XCD-grouped grid: the 10 blocks (2 m-chunks x 5 t) sharing one 0.59 MB
//   lab_e chunk run adjacently on the same XCD -> stream HBM once, then L2.
// - row norms fused: ssq of weighted rows + 8-lane shfl reduce.
__global__ __launch_bounds__(512, 4) void k_simf(const unsigned short* __restrict__ qnh,
                                                 const unsigned short* __restrict__ qnl,
                                                 const float* __restrict__ lab_e,
                                                 const float* __restrict__ w,
                                                 float* __restrict__ sim) {
    __shared__ unsigned short Ah[2][128*36], Al[2][128*36];
    __shared__ unsigned short Bh[2][128*36], Bl[2][128*36];
    __shared__ float rnl[128];

    // 157 n-chunks of 128 rows over 8 XCDs (xcd<5: 20, else 19), (m,t) innermost
    int bid = blockIdx.x;
    int xcd = bid & 7, s = bid >> 3;
    int cnt = (xcd < 5) ? 20 : 19;
    if (s >= cnt * 10) return;
    int start = (xcd < 5) ? xcd*20 : 100 + (xcd - 5)*19;
    int chunk = start + s / 10;
    int inner = s - (s / 10) * 10;
    int mch = inner / 5;
    int t = inner - mch * 5;
    int bn = chunk * 128;
    int bm = mch * 128;

    float w0 = w[t*3+0], w1 = w[t*3+1], w2 = w[t*3+2];
    int tid = threadIdx.x;
    int lane = tid & 63, wv = tid >> 6;
    int mbase = (wv >> 2)*64, nbase = (wv & 3)*32;
    int fr = lane & 15, kg = lane >> 4;

    // A staging role: one row chunk per thread (int4 = 8 ushorts per plane)
    int ar = tid >> 2, akq = tid & 3;
    const unsigned short* agh = qnh + ((size_t)t*B_ + bm + ar)*D_ + akq*8;
    const unsigned short* agl = qnl + ((size_t)t*B_ + bm + ar)*D_ + akq*8;
    int aoff = ar*36 + akq*8;

    // B staging role: two rows per thread (gr0, gr1), 4-col chunk kq
    int gr0 = tid >> 3, gr1 = 64 + (tid >> 3), kq = tid & 7;
    int gn0 = bn + gr0, gn1 = bn + gr1;
    bool v0 = gn0 < NLAB, v1 = gn1 < NLAB;
    const float* bp0 = lab_e + (size_t)gn0*(3*D_) + kq*4;
    const float* bp1 = lab_e + (size_t)gn1*(3*D_) + kq*4;
    int soff0 = gr0*36 + kq*4, soff1 = gr1*36 + kq*4;

    floatx4 acc[4][2];
#pragma unroll
    for (int mi = 0; mi < 4; ++mi)
#pragma unroll
        for (int ni = 0; ni < 2; ++ni)
            acc[mi][ni] = (floatx4){0.f, 0.f, 0.f, 0.f};

    float ss0 = 0.f, ss1 = 0.f;
    float4 rb0[3], rb1[3];
    float4 z4 = make_float4(0.f, 0.f, 0.f, 0.f);
    int4 lah, lal;

    // ---- prologue: load + stage tile 0 into buf0, then issue tile-1 loads ----
    rb0[0]=rb0[1]=rb0[2]=z4; rb1[0]=rb1[1]=rb1[2]=z4;
    if (v0) { rb0[0] = *(const float4*)(bp0);
              rb0[1] = *(const float4*)(bp0 + D_);
              rb0[2] = *(const float4*)(bp0 + 2*D_); }
    if (v1) { rb1[0] = *(const float4*)(bp1);
              rb1[1] = *(const float4*)(bp1 + D_);
              rb1[2] = *(const float4*)(bp1 + 2*D_); }
    lah = *(const int4*)(agh);
    lal = *(const int4*)(agl);

    *(int4*)(&Ah[0][aoff]) = lah;
    *(int4*)(&Al[0][aoff]) = lal;
    cvt_store4(rb0, w0, w1, w2, &Bh[0][0], &Bl[0][0], soff0, ss0);
    cvt_store4(rb1, w0, w1, w2, &Bh[0][0], &Bl[0][0], soff1, ss1);

    // issue tile-1 loads (fly across barrier + MFMA of tile 0)
    if (v0) { rb0[0] = *(const float4*)(bp0 + 32);
              rb0[1] = *(const float4*)(bp0 + D_ + 32);
              rb0[2] = *(const float4*)(bp0 + 2*D_ + 32); }
    if (v1) { rb1[0] = *(const float4*)(bp1 + 32);
              rb1[1] = *(const float4*)(bp1 + D_ + 32);
              rb1[2] = *(const float4*)(bp1 + 2*D_ + 32); }
    lah = *(const int4*)(agh + 32);
    lal = *(const int4*)(agl + 32);

    for (int kt = 0; kt < 24; ++kt) {
        int cur = kt & 1;
        barrier_lds_only();        // buf[cur] stage writes now visible

        // B fragments for this wave's 32-col slice
        bf16x8 bhf[2], blf[2];
#pragma unroll
        for (int ni = 0; ni < 2; ++ni) {
            int off = (nbase + ni*16 + fr)*36 + kg*8;
            bhf[ni] = *(const bf16x8*)(&Bh[cur][off]);
            blf[ni] = *(const bf16x8*)(&Bl[cur][off]);
        }
#pragma unroll
        for (int mi = 0; mi < 4; ++mi) {
            int off = (mbase + mi*16 + fr)*36 + kg*8;
            bf16x8 ahf = *(const bf16x8*)(&Ah[cur][off]);
            bf16x8 alf = *(const bf16x8*)(&Al[cur][off]);
#pragma unroll
            for (int ni = 0; ni < 2; ++ni) {
                floatx4 c = acc[mi][ni];
                c = __builtin_amdgcn_mfma_f32_16x16x32_bf16(ahf, bhf[ni], c, 0, 0, 0);
                c = __builtin_amdgcn_mfma_f32_16x16x32_bf16(alf, bhf[ni], c, 0, 0, 0);
                c = __builtin_amdgcn_mfma_f32_16x16x32_bf16(ahf, blf[ni], c, 0, 0, 0);
                acc[mi][ni] = c;
            }
        }
        if (kt < 23) {
            // stage tile kt+1 into the other buffer (vmcnt wait lands here,
            // ~1 full iteration after issue)
            int nxt = cur ^ 1;
            *(int4*)(&Ah[nxt][aoff]) = lah;
            *(int4*)(&Al[nxt][aoff]) = lal;
            cvt_store4(rb0, w0, w1, w2, &Bh[nxt][0], &Bl[nxt][0], soff0, ss0);
            cvt_store4(rb1, w0, w1, w2, &Bh[nxt][0], &Bl[nxt][0], soff1, ss1);
            if (kt < 22) {
                // issue tile kt+2 loads
                int k2 = (kt + 2) * 32;
                if (v0) { rb0[0] = *(const float4*)(bp0 + k2);
                          rb0[1] = *(const float4*)(bp0 + D_ + k2);
                          rb0[2] = *(const float4*)(bp0 + 2*D_ + k2); }
                if (v1) { rb1[0] = *(const float4*)(bp1 + k2);
                          rb1[1] = *(const float4*)(bp1 + D_ + k2);
                          rb1[2] = *(const float4*)(bp1 + 2*D_ + k2); }
                lah = *(const int4*)(agh + k2);
                lal = *(const int4*)(agl + k2);
            }
        }
    }

    // fold rn: reduce ssq across the 8 threads of each row
    float t0 = ss0, t1 = ss1;
#pragma unroll
    for (int m = 1; m <= 4; m <<= 1) { t0 += __shfl_xor(t0, m); t1 += __shfl_xor(t1, m); }
    if ((tid & 7) == 0) {
        rnl[tid >> 3]        = rsqrtf(t0 + 1e-8f);
        rnl[64 + (tid >> 3)] = rsqrtf(t1 + 1e-8f);
    }
    __syncthreads();

    float* st = sim + (size_t)t*B_*NLAB;
#pragma unroll
    for (int mi = 0; mi < 4; ++mi) {
        int m = bm + mbase + mi*16 + kg*4;
#pragma unroll
        for (int ni = 0; ni < 2; ++ni) {
            int nl = nbase + ni*16 + fr;
            int n = bn + nl;
            if (n < NLAB) {
                float rv = rnl[nl];
#pragma unroll
                for (int r2 = 0; r2 < 4; ++r2)
                    st[(size_t)(m + r2)*NLAB + n] = acc[mi][ni][r2] * rv;
            }
        }
    }
}

// per-row top-8, grid (B, T)
__global__ __launch_bounds__(256) void k_topk(const float* __restrict__ sim,
                                              int* __restrict__ idx_out) {
    int b = blockIdx.x;
    int t = blockIdx.y;
    int tid = threadIdx.x;
    const float* row = sim + ((size_t)t*B_ + b)*NLAB;
    float tv[8]; int ti[8];
#pragma unroll
    for (int k = 0; k < 8; ++k) { tv[k] = -3e38f; ti[k] = 0x7fffffff; }
    for (int n = tid; n < NLAB; n += 256) {
        float v = row[n];
        if (v > tv[7]) {
            tv[7] = v; ti[7] = n;
#pragma unroll
            for (int k = 7; k > 0; --k) {
                if (tv[k] > tv[k-1]) {
                    float fv = tv[k]; tv[k] = tv[k-1]; tv[k-1] = fv;
                    int fi = ti[k]; ti[k] = ti[k-1]; ti[k-1] = fi;
                }
            }
        }
    }
    __shared__ float sv[2048];
    __shared__ int   si[2048];
    __shared__ float pv[256];
    __shared__ int   pi[256];
    __shared__ int   pp[256];
#pragma unroll
    for (int k = 0; k < 8; ++k) { sv[tid*8+k] = tv[k]; si[tid*8+k] = ti[k]; }
    __syncthreads();
    for (int r = 0; r < 8; ++r) {
        float bv = -3e38f; int bi = 0x7fffffff; int bp = 0;
#pragma unroll
        for (int k = 0; k < 8; ++k) {
            int p = tid*8 + k;
            float v = sv[p]; int ii = si[p];
            if (v > bv || (v == bv && ii < bi)) { bv = v; bi = ii; bp = p; }
        }
        pv[tid] = bv; pi[tid] = bi; pp[tid] = bp;
        __syncthreads();
        for (int off = 128; off > 0; off >>= 1) {
            if (tid < off) {
                if (pv[tid+off] > pv[tid] || (pv[tid+off] == pv[tid] && pi[tid+off] < pi[tid])) {
                    pv[tid] = pv[tid+off]; pi[tid] = pi[tid+off]; pp[tid] = pp[tid+off];
                }
            }
            __syncthreads();
        }
        if (tid == 0) {
            idx_out[((size_t)b*T_ + t)*K_ + r] = pi[0];
            sv[pp[0]] = -3e38f;
        }
        __syncthreads();
    }
}

// build token planes (bf16 hi/lo, 768 cols) + trait vector tt
__global__ __launch_bounds__(256) void k_toks(const float* __restrict__ lab_e,
                                              const float* __restrict__ lab_t,
                                              const float* __restrict__ uc,
                                              const int* __restrict__ idx,
                                              unsigned short* __restrict__ tokh,
                                              unsigned short* __restrict__ tokl,
                                              float* __restrict__ tt) {
    int g = blockIdx.x;            // 0..NROW-1
    int bt = g / L_, l = g % L_;
    int b = bt / T_, t = bt % T_;
    size_t ro = (size_t)g*D_;
    if (l < K_) {
        int n = idx[(size_t)bt*K_ + l];
        for (int d = threadIdx.x; d < D_; d += 256) {
            size_t base = (size_t)n*(3*D_) + d;
            float v = (lab_e[base] + lab_e[base + D_] + lab_e[base + 2*D_]) * (1.f/3.f);
            unsigned short h = f2bf(v);
            tokh[ro + d] = h; tokl[ro + d] = f2bf(v - bf2f(h));
        }
        if (threadIdx.x == 0) tt[g] = lab_t[(size_t)n*T_ + t];
    } else {
        for (int d = threadIdx.x; d < D_; d += 256) {
            float v = uc[(size_t)b*D_ + d];
            unsigned short h = f2bf(v);
            tokh[ro + d] = h; tokl[ro + d] = f2bf(v - bf2f(h));
        }
        if (threadIdx.x == 0) tt[g] = 0.f;
    }
}

// convert+transpose weight K x N -> hi/lo planes [n][k]
__global__ void k_cvtw(const float* __restrict__ W,
                       unsigned short* __restrict__ th,
                       unsigned short* __restrict__ tl,
                       int Kd, int N) {
    int total = Kd * N;
    for (int id = blockIdx.x*256 + threadIdx.x; id < total; id += gridDim.x*256) {
        int n = id / Kd, k = id - n*Kd;
        float v = W[(size_t)k*N + n];
        unsigned short h = f2bf(v);
        th[id] = h; tl[id] = f2bf(v - bf2f(h));
    }
}

// split-bf16 MFMA GEMM from pre-converted planes.
// A: M x Kd (hi/lo), B(transposed): N x Kd (hi/lo), C: M x N fp32.
// BM=128, BN=64, BK=32; 256 threads / 4 waves, wave = 64x32 (4x2 frags)
template<bool ADD, bool BIAS, bool TRAIT>
__global__ __launch_bounds__(256) void k_mgemm(const unsigned short* __restrict__ ah,
                                               const unsigned short* __restrict__ al,
                                               const unsigned short* __restrict__ bh,
                                               const unsigned short* __restrict__ bl,
                                               const float* __restrict__ bias,
                                               const float* __restrict__ wtrait,
                                               const float* __restrict__ tt,
                                               float* __restrict__ C,
                                               int N, int Kd) {
    __shared__ unsigned short Ah[128*40], Al[128*40], Bh[64*40], Bl[64*40];
    int bn = blockIdx.x * 64;
    int bm = blockIdx.y * 128;
    int tid = threadIdx.x;
    int lane = tid & 63, wv = tid >> 6;
    int mbase = (wv >> 1)*64, nbase = (wv & 1)*32;
    int fr = lane & 15, kg = lane >> 4;
    floatx4 acc[4][2];
#pragma unroll
    for (int mi = 0; mi < 4; ++mi)
#pragma unroll
        for (int ni = 0; ni < 2; ++ni)
            acc[mi][ni] = (floatx4){0.f, 0.f, 0.f, 0.f};

    for (int k0 = 0; k0 < Kd; k0 += 32) {
#pragma unroll
        for (int f = 0; f < 2; ++f) {
            int v = f*256 + tid;
            int r = v >> 2, kq = v & 3;
            size_t g = (size_t)(bm + r)*Kd + k0 + kq*8;
            int off = r*40 + kq*8;
            *(int4*)(Ah + off) = *(const int4*)(ah + g);
            *(int4*)(Al + off) = *(const int4*)(al + g);
        }
        {
            int r = tid >> 2, kq = tid & 3;
            size_t g = (size_t)(bn + r)*Kd + k0 + kq*8;
            int off = r*40 + kq*8;
            *(int4*)(Bh + off) = *(const int4*)(bh + g);
            *(int4*)(Bl + off) = *(const int4*)(bl + g);
        }
        __syncthreads();

        bf16x8 bhf[2], blf[2];
#pragma unroll
        for (int ni = 0; ni < 2; ++ni) {
            int off = (nbase + ni*16 + fr)*40 + kg*8;
            bhf[ni] = *(const bf16x8*)(Bh + off);
            blf[ni] = *(const bf16x8*)(Bl + off);
        }
#pragma unroll
        for (int mi = 0; mi < 4; ++mi) {
            int off = (mbase + mi*16 + fr)*40 + kg*8;
            bf16x8 ahf = *(const bf16x8*)(Ah + off);
            bf16x8 alf = *(const bf16x8*)(Al + off);
#pragma unroll
            for (int ni = 0; ni < 2; ++ni) {
                floatx4 c = acc[mi][ni];
                c = __builtin_amdgcn_mfma_f32_16x16x32_bf16(ahf, bhf[ni], c, 0, 0, 0);
                c = __builtin_amdgcn_mfma_f32_16x16x32_bf16(alf, bhf[ni], c, 0, 0, 0);
                c = __builtin_amdgcn_mfma_f32_16x16x32_bf16(ahf, blf[ni], c, 0, 0, 0);
                acc[mi][ni] = c;
            }
        }
        __syncthreads();
    }
#pragma unroll
    for (int mi = 0; mi < 4; ++mi) {
        int m0 = bm + mbase + mi*16 + kg*4;
#pragma unroll
        for (int ni = 0; ni < 2; ++ni) {
            int n = bn + nbase + ni*16 + fr;
#pragma unroll
            for (int r = 0; r < 4; ++r) {
                float v = acc[mi][ni][r];
                if (TRAIT) v += tt[m0 + r] * wtrait[n];
                if (BIAS)  v += bias[n];
                size_t o = (size_t)(m0 + r)*N + n;
                if (ADD) C[o] += v; else C[o] = v;
            }
        }
    }
}

// layer norm -> fp32 out + bf16 hi/lo planes
__global__ __launch_bounds__(256) void k_ln(const float* __restrict__ x,
                                            const float* __restrict__ g,
                                            const float* __restrict__ b,
                                            float* __restrict__ xn,
                                            unsigned short* __restrict__ xnh,
                                            unsigned short* __restrict__ xnl) {
    int row = blockIdx.x, tid = threadIdx.x;
    float v = x[(size_t)row*H_ + tid];
    float mean = block_reduce_sum(v) * (1.f/H_);
    float d = v - mean;
    float var = block_reduce_sum(d*d) * (1.f/H_);
    float o = d * rsqrtf(var + 1e-5f) * g[tid] + b[tid];
    size_t oo = (size_t)row*H_ + tid;
    xn[oo] = o;
    unsigned short h = f2bf(o);
    xnh[oo] = h; xnl[oo] = f2bf(o - bf2f(h));
}

// fused mamba inner chain: conv+silu -> dbl (MFMA) -> dt -> selective scan -> gate.
// block = one sequence (n), 512 threads = one per d channel.
// LDS: xc [9][516] (padded), dbl [9][48].  Wx^T pre-converted to bf16 hi/lo planes.
__global__ __launch_bounds__(512) void k_mamba(const float* __restrict__ xz,
                                               const float* __restrict__ cw,
                                               const float* __restrict__ cb,
                                               const unsigned short* __restrict__ wxh,
                                               const unsigned short* __restrict__ wxl,
                                               const float* __restrict__ Wdt,
                                               const float* __restrict__ bdt,
                                               const float* __restrict__ A_log,
                                               const float* __restrict__ Dp,
                                               unsigned short* __restrict__ yh,
                                               unsigned short* __restrict__ yl) {
    __shared__ float xcS[L_][516];
    __shared__ float dblS[L_][48];
    int n = blockIdx.x, d = threadIdx.x;

    // ---- causal conv (KC=4) + silu; keep xc and z in registers ----
    float c0 = cw[d*4+0], c1 = cw[d*4+1], c2 = cw[d*4+2], c3 = cw[d*4+3];
    float bb = cb[d];
    const float* src = xz + (size_t)n*L_*(2*DI_) + d;
    float xc[L_], z[L_];
    float x0 = 0.f, x1 = 0.f, x2 = 0.f;
#pragma unroll
    for (int l = 0; l < L_; ++l) {
        float x3 = src[l*(2*DI_)];
        z[l]     = src[l*(2*DI_) + DI_];
        float s = bb + c0*x0 + c1*x1 + c2*x2 + c3*x3;
        float v = siluf_(s);
        xc[l] = v; xcS[l][d] = v;
        x0 = x1; x1 = x2; x2 = x3;
    }
    __syncthreads();

    // ---- dbl = xc(9x512) @ Wx(512x48) via split-bf16 MFMA on waves 0..2 ----
    int wv = d >> 6, lane = d & 63;
    if (wv < 3) {
        int fr = lane & 15, kg = lane >> 4;
        const unsigned short* bph = wxh + (size_t)(wv*16 + fr)*DI_;
        const unsigned short* bpl = wxl + (size_t)(wv*16 + fr)*DI_;
        floatx4 c = (floatx4){0.f, 0.f, 0.f, 0.f};
        for (int k0 = 0; k0 < DI_; k0 += 32) {
            int kb = k0 + kg*8;
            float av[8];
            if (fr < L_) {
                float4 q0 = *(const float4*)(&xcS[fr][kb]);
                float4 q1 = *(const float4*)(&xcS[fr][kb+4]);
                av[0]=q0.x; av[1]=q0.y; av[2]=q0.z; av[3]=q0.w;
                av[4]=q1.x; av[5]=q1.y; av[6]=q1.z; av[7]=q1.w;
            } else {
#pragma unroll
                for (int j = 0; j < 8; ++j) av[j] = 0.f;
            }
            bf16x8 ah, al;
#pragma unroll
            for (int j = 0; j < 8; ++j) {
                unsigned short hh = f2bf(av[j]);
                ah[j] = (short)hh;
                al[j] = (short)f2bf(av[j] - bf2f(hh));
            }
            bf16x8 bhf = *(const bf16x8*)(bph + kb);
            bf16x8 blf = *(const bf16x8*)(bpl + kb);
            c = __builtin_amdgcn_mfma_f32_16x16x32_bf16(ah, bhf, c, 0, 0, 0);
            c = __builtin_amdgcn_mfma_f32_16x16x32_bf16(al, bhf, c, 0, 0, 0);
            c = __builtin_amdgcn_mfma_f32_16x16x32_bf16(ah, blf, c, 0, 0, 0);
        }
#pragma unroll
        for (int r = 0; r < 4; ++r) {
            int row = kg*4 + r;
            if (row < L_) dblS[row][wv*16 + fr] = c[r];
        }
    }
    __syncthreads();

    // ---- dt + selective scan + gate, per-thread channel d ----
    float a[S_], wdt[R_];
#pragma unroll
    for (int s = 0; s < S_; ++s) a[s] = -expf(A_log[(size_t)d*S_ + s]);
#pragma unroll
    for (int r = 0; r < R_; ++r) wdt[r] = Wdt[(size_t)r*DI_ + d];
    float bdtv = bdt[d], dp = Dp[d];
    float h[S_];
#pragma unroll
    for (int s = 0; s < S_; ++s) h[s] = 0.f;
    size_t ob = (size_t)n*L_*DI_ + d;
#pragma unroll
    for (int l = 0; l < L_; ++l) {
        float s = bdtv;
#pragma unroll
        for (int r = 0; r < R_; ++r) s = fmaf(dblS[l][r], wdt[r], s);
        float dtv = softplusf_(s);
        float xcv = xc[l];
        float accv = 0.f;
#pragma unroll
        for (int si = 0; si < S_; ++si) {
            float Bv = dblS[l][16 + si], Cv = dblS[l][32 + si];
            h[si] = expf(dtv*a[si])*h[si] + dtv*Bv*xcv;
            accv = fmaf(h[si], Cv, accv);
        }
        float yv = (accv + dp*xcv) * siluf_(z[l]);
        unsigned short hh = f2bf(yv);
        yh[ob + (size_t)l*DI_] = hh;
        yl[ob + (size_t)l*DI_] = f2bf(yv - bf2f(hh));
    }
}

// head
__global__ __launch_bounds__(128) void k_head(const float* __restrict__ x,
                                              const float* __restrict__ W1,
                                              const float* __restrict__ b1,
                                              const float* __restrict__ W2,
                                              const float* __restrict__ b2,
                                              float* __restrict__ out) {
    int n = blockIdx.x, tid = threadIdx.x;
    __shared__ float ms[H_];
    const float* src = x + ((size_t)n*L_ + (L_-1))*H_;
    ms[tid] = src[tid];
    ms[tid+128] = src[tid+128];
    __syncthreads();
    float s = b1[tid];
#pragma unroll 8
    for (int k = 0; k < H_; ++k) s = fmaf(ms[k], W1[(size_t)k*128 + tid], s);
    float h = fmaxf(s, 0.f);
    float p = h * W2[tid];
    float tot = block_reduce_sum(p);
    if (tid == 0) out[n] = tot + b2[0];
}

// ---------------- launch ----------------

extern "C" void kernel_launch(void* const* d_in, const int* in_sizes, int n_in,
                              void* d_out, int out_size, void* d_ws, size_t ws_size,
                              hipStream_t stream) {
    const float* unl   = (const float*)d_in[0];
    const float* lab_e = (const float*)d_in[1];
    const float* lab_t = (const float*)d_in[2];
    const float* mlog  = (const float*)d_in[3];
    const float* Wp    = (const float*)d_in[4];
    const float* bp    = (const float*)d_in[5];
    const float* ln_g  = (const float*)d_in[6];
    const float* ln_b  = (const float*)d_in[7];
    const float* Win   = (const float*)d_in[8];
    const float* conv_w= (const float*)d_in[9];
    const float* conv_b= (const float*)d_in[10];
    const float* Wx    = (const float*)d_in[11];
    const float* Wdt   = (const float*)d_in[12];
    const float* bdt   = (const float*)d_in[13];
    const float* A_log = (const float*)d_in[14];
    const float* Dp    = (const float*)d_in[15];
    const float* Wout  = (const float*)d_in[16];
    const float* W1    = (const float*)d_in[17];
    const float* b1    = (const float*)d_in[18];
    const float* W2    = (const float*)d_in[19];
    const float* b2    = (const float*)d_in[20];

    float* ws = (float*)d_ws;
    // fixed layout (float units); ushort buffers cast from 4-aligned float offsets
    float* w    = ws + 0;                                    // 16
    int*   idx  = (int*)(ws + 16);                           // 10240 ints
    float* uc   = ws + 10256;                                // 196,608
    // old rn slot (100,000 floats) repurposed for Wx^T bf16 planes (4 layers)
    unsigned short* wxth = (unsigned short*)(ws + 206864);   // 98,304 ush = 49,152 f
    unsigned short* wxtl = (unsigned short*)(ws + 256016);   // 98,304 ush
    float* tt   = ws + 306864;                               // 11,520
    unsigned short* qnh   = (unsigned short*)(ws + 318384);  // 983,040 ush
    unsigned short* qnl   = (unsigned short*)(ws + 809904);
    unsigned short* wph   = (unsigned short*)(ws + 1301424); // 196,608 ush
    unsigned short* wpl   = (unsigned short*)(ws + 1399728);
    unsigned short* winh  = (unsigned short*)(ws + 1498032); // 1,048,576 ush
    unsigned short* winl  = (unsigned short*)(ws + 2022320);
    unsigned short* wouth = (unsigned short*)(ws + 2546608); // 524,288 ush
    unsigned short* woutl = (unsigned short*)(ws + 2808752);
    float* xa   = ws + 3070896;                              // 2,949,120
    float* xb   = ws + 6020016;                              // 2,949,120
    unsigned short* xnh   = (unsigned short*)(ws + 8969136); // 2,949,120 ush
    unsigned short* xnl   = (unsigned short*)(ws + 10443696);
    float* simreg = ws + 18369456;                           // 25,600,000
    float* sim  = simreg;
    float* xz   = simreg;                                    // 11,796,480 (phase 2)
    unsigned short* tokh = (unsigned short*)(simreg + 11796480); // 8,847,360 ush (dead before xz phase-2 grows)
    unsigned short* tokl = (unsigned short*)(simreg + 16220160);
    unsigned short* yh   = (unsigned short*)(simreg + 17694720); // 5,898,240 ush
    unsigned short* yl   = (unsigned short*)(simreg + 20643840);

    k_softmax_w<<<1, 64, 0, stream>>>(mlog, w);
    k_qn_uc<<<B_, 256, 0, stream>>>(unl, w, qnh, qnl, uc);
    // weight conversions (once per call)
    k_cvtw<<<(768*256 + 255)/256, 256, 0, stream>>>(Wp, wph, wpl, 768, 256);
    for (int i = 0; i < NL_; ++i) {
        k_cvtw<<<(256*1024 + 255)/256, 256, 0, stream>>>(Win + (size_t)i*H_*(2*DI_),
                                                         winh + (size_t)i*H_*(2*DI_),
                                                         winl + (size_t)i*H_*(2*DI_), 256, 1024);
        k_cvtw<<<(512*256 + 255)/256, 256, 0, stream>>>(Wout + (size_t)i*DI_*H_,
                                                        wouth + (size_t)i*DI_*H_,
                                                        woutl + (size_t)i*DI_*H_, 512, 256);
        k_cvtw<<<(512*48 + 255)/256, 256, 0, stream>>>(Wx + (size_t)i*DI_*48,
                                                       wxth + (size_t)i*48*DI_,
                                                       wxtl + (size_t)i*48*DI_, 512, 48);
    }
    k_simf<<<1600, 512, 0, stream>>>(qnh, qnl, lab_e, w, sim);
    {
        dim3 g(B_, T_);
        k_topk<<<g, 256, 0, stream>>>(sim, idx);
    }
    k_toks<<<NROW, 256, 0, stream>>>(lab_e, lab_t, uc, idx, tokh, tokl, tt);
    {
        dim3 g(H_/64, NROW/128);
        k_mgemm<false,true,true><<<g, 256, 0, stream>>>(tokh, tokl, wph, wpl,
                                                        bp, Wp + (size_t)768*H_, tt, xa, H_, D_);
    }
    float* cur = xa;
    float* oth = xb;
    for (int i = 0; i < NL_; ++i) {
        k_ln<<<NROW, 256, 0, stream>>>(cur, ln_g + (size_t)i*H_, ln_b + (size_t)i*H_, oth, xnh, xnl);
        {
            dim3 g((2*DI_)/64, NROW/128);
            k_mgemm<false,false,false><<<g, 256, 0, stream>>>(xnh, xnl,
                winh + (size_t)i*H_*(2*DI_), winl + (size_t)i*H_*(2*DI_),
                nullptr, nullptr, nullptr, xz, 2*DI_, H_);
        }
        k_mamba<<<NBT, 512, 0, stream>>>(xz,
                                         conv_w + (size_t)i*DI_*KC_, conv_b + (size_t)i*DI_,
                                         wxth + (size_t)i*48*DI_, wxtl + (size_t)i*48*DI_,
                                         Wdt + (size_t)i*R_*DI_, bdt + (size_t)i*DI_,
                                         A_log + (size_t)i*DI_*S_, Dp + (size_t)i*DI_,
                                         yh, yl);
        {
            dim3 g(H_/64, NROW/128);
            k_mgemm<true,false,false><<<g, 256, 0, stream>>>(yh, yl,
                wouth + (size_t)i*DI_*H_, woutl + (size_t)i*DI_*H_,
                nullptr, nullptr, nullptr, oth, H_, DI_);
        }
        float* tmp = cur; cur = oth; oth = tmp;
    }
    k_head<<<NBT, 128, 0, stream>>>(cur, W1, b1, W2, b2, (float*)d_out);
}

// Round 5
// 1391.562 us; speedup vs baseline: 1.3739x; 1.0180x over previous
//
#include <hip/hip_runtime.h>
#include <math.h>

#define B_   256
#define NLAB 20000
#define M_   3
#define D_   768
#define T_   5
#define K_   8
#define H_   256
#define DI_  512
#define S_   16
#define R_   16
#define NL_  4
#define KC_  4
#define L_   9          // K+1 tokens
#define NBT  1280       // B*T sequences
#define NROW 11520      // NBT*L flattened rows

typedef __attribute__((ext_vector_type(8))) short bf16x8;
typedef __attribute__((ext_vector_type(4))) float floatx4;

// ---------------- helpers ----------------

__device__ __forceinline__ float block_reduce_sum(float v) {
    __shared__ float red[4];
    int lane = threadIdx.x & 63;
    int wid  = threadIdx.x >> 6;
#pragma unroll
    for (int o = 32; o > 0; o >>= 1) v += __shfl_down(v, o);
    if (lane == 0) red[wid] = v;
    __syncthreads();
    int nw = (int)(blockDim.x >> 6);
    float r = 0.f;
#pragma unroll
    for (int i = 0; i < 4; ++i) if (i < nw) r += red[i];
    __syncthreads();
    return r;
}

__device__ __forceinline__ float sigmoidf_(float x) { return 1.f / (1.f + expf(-x)); }
__device__ __forceinline__ float siluf_(float x)    { return x * sigmoidf_(x); }
__device__ __forceinline__ float softplusf_(float x){ return x > 20.f ? x : log1pf(expf(x)); }

// fp32 -> bf16 via hardware convert (v_cvt_pk_bf16_f32, RNE); the old manual
// RNE bit-trick cost ~4-5 VALU instrs per value and was 34% VALUBusy in k_simf.
__device__ __forceinline__ unsigned short f2bf(float x) {
    return __builtin_bit_cast(unsigned short, (__bf16)x);
}
__device__ __forceinline__ float bf2f(unsigned short h) {
    return (float)__builtin_bit_cast(__bf16, h);
}

// barrier that does NOT drain vmcnt: LDS ordering only.  Global register loads
// issued before this stay in flight across the barrier.
__device__ __forceinline__ void barrier_lds_only() {
    asm volatile("s_waitcnt lgkmcnt(0)" ::: "memory");
    __builtin_amdgcn_s_barrier();
}

// ---------------- kernels ----------------

__global__ void k_softmax_w(const float* __restrict__ mlog, float* __restrict__ w) {
    int t = threadIdx.x;
    if (t < T_) {
        float a = mlog[t*M_+0], b = mlog[t*M_+1], c = mlog[t*M_+2];
        float mx = fmaxf(a, fmaxf(b, c));
        float ea = expf(a-mx), eb = expf(b-mx), ec = expf(c-mx);
        float s = ea + eb + ec;
        w[t*M_+0] = ea/s; w[t*M_+1] = eb/s; w[t*M_+2] = ec/s;
    }
}

// qn (normalized queries) -> bf16 hi/lo planes ; uc = mean over m
__global__ __launch_bounds__(256) void k_qn_uc(const float* __restrict__ unl,
                                               const float* __restrict__ w,
                                               unsigned short* __restrict__ qnh,
                                               unsigned short* __restrict__ qnl,
                                               float* __restrict__ uc) {
    int b = blockIdx.x, tid = threadIdx.x;
    float e[3][3];
#pragma unroll
    for (int c = 0; c < 3; ++c) {
        int d = tid + c*256;
#pragma unroll
        for (int m = 0; m < 3; ++m)
            e[c][m] = unl[((size_t)b*3 + m)*D_ + d];
    }
#pragma unroll
    for (int c = 0; c < 3; ++c)
        uc[(size_t)b*D_ + tid + c*256] = (e[c][0] + e[c][1] + e[c][2]) * (1.f/3.f);
    for (int t = 0; t < T_; ++t) {
        float w0 = w[t*3+0], w1 = w[t*3+1], w2 = w[t*3+2];
        float q[3]; float ss = 0.f;
#pragma unroll
        for (int c = 0; c < 3; ++c) {
            q[c] = w0*e[c][0] + w1*e[c][1] + w2*e[c][2];
            ss += q[c]*q[c];
        }
        float tot = block_reduce_sum(ss);
        float inv = rsqrtf(tot + 1e-8f);
#pragma unroll
        for (int c = 0; c < 3; ++c) {
            float v = q[c]*inv;
            size_t o = ((size_t)t*B_ + b)*D_ + tid + c*256;
            unsigned short h = f2bf(v);
            qnh[o] = h; qnl[o] = f2bf(v - bf2f(h));
        }
    }
}

// weight+ssq+split-bf16 convert of one staged row chunk, store to LDS
__device__ __forceinline__ void cvt_store4(const float4* rb, float w0, float w1, float w2,
                                           unsigned short* bh, unsigned short* bl,
                                           int off, float& ss) {
    float4 s;
    s.x = w0*rb[0].x + w1*rb[1].x + w2*rb[2].x;
    s.y = w0*rb[0].y + w1*rb[1].y + w2*rb[2].y;
    s.z = w0*rb[0].z + w1*rb[1].z + w2*rb[2].z;
    s.w = w0*rb[0].w + w1*rb[1].w + w2*rb[2].w;
    ss += s.x*s.x + s.y*s.y + s.z*s.z + s.w*s.w;
    ushort4 h, l;
    h.x = f2bf(s.x); l.x = f2bf(s.x - bf2f(h.x));
    h.y = f2bf(s.y); l.y = f2bf(s.y - bf2f(h.y));
    h.z = f2bf(s.z); l.z = f2bf(s.z - bf2f(h.z));
    h.w = f2bf(s.w); l.w = f2bf(s.w - bf2f(h.w));
    *(ushort4*)(bh + off) = h;
    *(ushort4*)(bl + off) = l;
}

// split-bf16 MFMA sim GEMM.  BM=128, BN=128, BK=32; 512 threads / 8 waves
// (2m x 4n), wave tile 64x32 -> acc[4][2] = 32 VGPR.
// - SINGLE-buffered A+B in LDS, pad 40 (16B-aligned rows; round-4's pad-36 put
//   odd rows at 8 mod 16 -> misaligned ds_read_b128 slow path).  41 KB LDS ->
//   3 blocks/CU = 24 waves/CU; three UNSYNCHRONIZED blocks per CU hide the
//   barrier stalls better than intra-block double-buffering (m114 overlap).
// - Two lgkm-only barriers per K-tile; neither drains vmcnt, so the register
//   prefetch of tile kt+1 (issued mid-iteration) stays in flight across both.
// - hardware bf16 converts (f2bf -> v_cvt_pk_bf16_f32) cut the convert VALU.
// - XCD-grouped grid: the 10 blocks (2 m-chunks x 5 t) sharing one lab_e chunk
//   run adjacently on the same XCD -> stream HBM once, then L2.
// - row norms fused: ssq of weighted rows + 8-lane shfl reduce.
__global__ __launch_bounds__(512, 8) void k_simf(const unsigned short* __restrict__ qnh,
                                                 const unsigned short* __restrict__ qnl,
                                                 const float* __restrict__ lab_e,
                                                 const float* __restrict__ w,
                                                 float* __restrict__ sim) {
    __shared__ unsigned short Ah[128*40], Al[128*40];
    __shared__ unsigned short Bh[128*40], Bl[128*40];
    __shared__ float rnl[128];

    // 157 n-chunks of 128 rows over 8 XCDs (xcd<5: 20, else 19), (m,t) innermost
    int bid = blockIdx.x;
    int xcd = bid & 7, sb = bid >> 3;
    int cnt = (xcd < 5) ? 20 : 19;
    if (sb >= cnt * 10) return;
    int start = (xcd < 5) ? xcd*20 : 100 + (xcd - 5)*19;
    int chunk = start + sb / 10;
    int inner = sb - (sb / 10) * 10;
    int mch = inner / 5;
    int t = inner - mch * 5;
    int bn = chunk * 128;
    int bm = mch * 128;

    float w0 = w[t*3+0], w1 = w[t*3+1], w2 = w[t*3+2];
    int tid = threadIdx.x;
    int lane = tid & 63, wv = tid >> 6;
    int mbase = (wv >> 2)*64, nbase = (wv & 3)*32;
    int fr = lane & 15, kg = lane >> 4;

    // A staging role: one row chunk per thread (int4 = 8 ushorts per plane)
    int ar = tid >> 2, akq = tid & 3;
    const unsigned short* agh = qnh + ((size_t)t*B_ + bm + ar)*D_ + akq*8;
    const unsigned short* agl = qnl + ((size_t)t*B_ + bm + ar)*D_ + akq*8;
    int aoff = ar*40 + akq*8;

    // B staging role: two rows per thread (gr0, gr1), 4-col chunk kq
    int gr0 = tid >> 3, gr1 = 64 + (tid >> 3), kq = tid & 7;
    int gn0 = bn + gr0, gn1 = bn + gr1;
    bool v0 = gn0 < NLAB, v1 = gn1 < NLAB;
    const float* bp0 = lab_e + (size_t)gn0*(3*D_) + kq*4;
    const float* bp1 = lab_e + (size_t)gn1*(3*D_) + kq*4;
    int soff0 = gr0*40 + kq*4, soff1 = gr1*40 + kq*4;

    floatx4 acc[4][2];
#pragma unroll
    for (int mi = 0; mi < 4; ++mi)
#pragma unroll
        for (int ni = 0; ni < 2; ++ni)
            acc[mi][ni] = (floatx4){0.f, 0.f, 0.f, 0.f};

    float ss0 = 0.f, ss1 = 0.f;
    float4 rb0[3], rb1[3];
    float4 z4 = make_float4(0.f, 0.f, 0.f, 0.f);
    int4 lah, lal;

    // prologue: load raw tile 0 into registers
    rb0[0]=rb0[1]=rb0[2]=z4; rb1[0]=rb1[1]=rb1[2]=z4;
    if (v0) { rb0[0] = *(const float4*)(bp0);
              rb0[1] = *(const float4*)(bp0 + D_);
              rb0[2] = *(const float4*)(bp0 + 2*D_); }
    if (v1) { rb1[0] = *(const float4*)(bp1);
              rb1[1] = *(const float4*)(bp1 + D_);
              rb1[2] = *(const float4*)(bp1 + 2*D_); }
    lah = *(const int4*)(agh);
    lal = *(const int4*)(agl);

    for (int kt = 0; kt < 24; ++kt) {
        barrier_lds_only();        // all waves done reading previous tile frags

        // stage tile kt (registers -> LDS); compiler inserts precise vmcnt waits
        *(int4*)(&Ah[aoff]) = lah;
        *(int4*)(&Al[aoff]) = lal;
        cvt_store4(rb0, w0, w1, w2, Bh, Bl, soff0, ss0);
        cvt_store4(rb1, w0, w1, w2, Bh, Bl, soff1, ss1);

        // issue raw loads for tile kt+1 — they fly across both barriers and
        // the MFMA phase (neither barrier drains vmcnt)
        if (kt < 23) {
            int k2 = (kt + 1) * 32;
            if (v0) { rb0[0] = *(const float4*)(bp0 + k2);
                      rb0[1] = *(const float4*)(bp0 + D_ + k2);
                      rb0[2] = *(const float4*)(bp0 + 2*D_ + k2); }
            if (v1) { rb1[0] = *(const float4*)(bp1 + k2);
                      rb1[1] = *(const float4*)(bp1 + D_ + k2);
                      rb1[2] = *(const float4*)(bp1 + 2*D_ + k2); }
            lah = *(const int4*)(agh + k2);
            lal = *(const int4*)(agl + k2);
        }

        barrier_lds_only();        // stage writes visible

        bf16x8 bhf[2], blf[2];
#pragma unroll
        for (int ni = 0; ni < 2; ++ni) {
            int off = (nbase + ni*16 + fr)*40 + kg*8;
            bhf[ni] = *(const bf16x8*)(Bh + off);
            blf[ni] = *(const bf16x8*)(Bl + off);
        }
#pragma unroll
        for (int mi = 0; mi < 4; ++mi) {
            int off = (mbase + mi*16 + fr)*40 + kg*8;
            bf16x8 ahf = *(const bf16x8*)(Ah + off);
            bf16x8 alf = *(const bf16x8*)(Al + off);
#pragma unroll
            for (int ni = 0; ni < 2; ++ni) {
                floatx4 c = acc[mi][ni];
                c = __builtin_amdgcn_mfma_f32_16x16x32_bf16(ahf, bhf[ni], c, 0, 0, 0);
                c = __builtin_amdgcn_mfma_f32_16x16x32_bf16(alf, bhf[ni], c, 0, 0, 0);
                c = __builtin_amdgcn_mfma_f32_16x16x32_bf16(ahf, blf[ni], c, 0, 0, 0);
                acc[mi][ni] = c;
            }
        }
    }

    // fold rn: reduce ssq across the 8 threads of each row
    float t0 = ss0, t1 = ss1;
#pragma unroll
    for (int m = 1; m <= 4; m <<= 1) { t0 += __shfl_xor(t0, m); t1 += __shfl_xor(t1, m); }
    if ((tid & 7) == 0) {
        rnl[tid >> 3]        = rsqrtf(t0 + 1e-8f);
        rnl[64 + (tid >> 3)] = rsqrtf(t1 + 1e-8f);
    }
    __syncthreads();

    float* st = sim + (size_t)t*B_*NLAB;
#pragma unroll
    for (int mi = 0; mi < 4; ++mi) {
        int m = bm + mbase + mi*16 + kg*4;
#pragma unroll
        for (int ni = 0; ni < 2; ++ni) {
            int nl = nbase + ni*16 + fr;
            int n = bn + nl;
            if (n < NLAB) {
                float rv = rnl[nl];
#pragma unroll
                for (int r2 = 0; r2 < 4; ++r2)
                    st[(size_t)(m + r2)*NLAB + n] = acc[mi][ni][r2] * rv;
            }
        }
    }
}

// per-row top-8, grid (B, T)
__global__ __launch_bounds__(256) void k_topk(const float* __restrict__ sim,
                                              int* __restrict__ idx_out) {
    int b = blockIdx.x;
    int t = blockIdx.y;
    int tid = threadIdx.x;
    const float* row = sim + ((size_t)t*B_ + b)*NLAB;
    float tv[8]; int ti[8];
#pragma unroll
    for (int k = 0; k < 8; ++k) { tv[k] = -3e38f; ti[k] = 0x7fffffff; }
    for (int n = tid; n < NLAB; n += 256) {
        float v = row[n];
        if (v > tv[7]) {
            tv[7] = v; ti[7] = n;
#pragma unroll
            for (int k = 7; k > 0; --k) {
                if (tv[k] > tv[k-1]) {
                    float fv = tv[k]; tv[k] = tv[k-1]; tv[k-1] = fv;
                    int fi = ti[k]; ti[k] = ti[k-1]; ti[k-1] = fi;
                }
            }
        }
    }
    __shared__ float sv[2048];
    __shared__ int   si[2048];
    __shared__ float pv[256];
    __shared__ int   pi[256];
    __shared__ int   pp[256];
#pragma unroll
    for (int k = 0; k < 8; ++k) { sv[tid*8+k] = tv[k]; si[tid*8+k] = ti[k]; }
    __syncthreads();
    for (int r = 0; r < 8; ++r) {
        float bv = -3e38f; int bi = 0x7fffffff; int bp = 0;
#pragma unroll
        for (int k = 0; k < 8; ++k) {
            int p = tid*8 + k;
            float v = sv[p]; int ii = si[p];
            if (v > bv || (v == bv && ii < bi)) { bv = v; bi = ii; bp = p; }
        }
        pv[tid] = bv; pi[tid] = bi; pp[tid] = bp;
        __syncthreads();
        for (int off = 128; off > 0; off >>= 1) {
            if (tid < off) {
                if (pv[tid+off] > pv[tid] || (pv[tid+off] == pv[tid] && pi[tid+off] < pi[tid])) {
                    pv[tid] = pv[tid+off]; pi[tid] = pi[tid+off]; pp[tid] = pp[tid+off];
                }
            }
            __syncthreads();
        }
        if (tid == 0) {
            idx_out[((size_t)b*T_ + t)*K_ + r] = pi[0];
            sv[pp[0]] = -3e38f;
        }
        __syncthreads();
    }
}

// build token planes (bf16 hi/lo, 768 cols) + trait vector tt
__global__ __launch_bounds__(256) void k_toks(const float* __restrict__ lab_e,
                                              const float* __restrict__ lab_t,
                                              const float* __restrict__ uc,
                                              const int* __restrict__ idx,
                                              unsigned short* __restrict__ tokh,
                                              unsigned short* __restrict__ tokl,
                                              float* __restrict__ tt) {
    int g = blockIdx.x;            // 0..NROW-1
    int bt = g / L_, l = g % L_;
    int b = bt / T_, t = bt % T_;
    size_t ro = (size_t)g*D_;
    if (l < K_) {
        int n = idx[(size_t)bt*K_ + l];
        for (int d = threadIdx.x; d < D_; d += 256) {
            size_t base = (size_t)n*(3*D_) + d;
            float v = (lab_e[base] + lab_e[base + D_] + lab_e[base + 2*D_]) * (1.f/3.f);
            unsigned short h = f2bf(v);
            tokh[ro + d] = h; tokl[ro + d] = f2bf(v - bf2f(h));
        }
        if (threadIdx.x == 0) tt[g] = lab_t[(size_t)n*T_ + t];
    } else {
        for (int d = threadIdx.x; d < D_; d += 256) {
            float v = uc[(size_t)b*D_ + d];
            unsigned short h = f2bf(v);
            tokh[ro + d] = h; tokl[ro + d] = f2bf(v - bf2f(h));
        }
        if (threadIdx.x == 0) tt[g] = 0.f;
    }
}

// convert+transpose weight K x N -> hi/lo planes [n][k]
__global__ void k_cvtw(const float* __restrict__ W,
                       unsigned short* __restrict__ th,
                       unsigned short* __restrict__ tl,
                       int Kd, int N) {
    int total = Kd * N;
    for (int id = blockIdx.x*256 + threadIdx.x; id < total; id += gridDim.x*256) {
        int n = id / Kd, k = id - n*Kd;
        float v = W[(size_t)k*N + n];
        unsigned short h = f2bf(v);
        th[id] = h; tl[id] = f2bf(v - bf2f(h));
    }
}

// split-bf16 MFMA GEMM from pre-converted planes.
// A: M x Kd (hi/lo), B(transposed): N x Kd (hi/lo), C: M x N fp32.
// BM=128, BN=64, BK=32; 256 threads / 4 waves, wave = 64x32 (4x2 frags)
template<bool ADD, bool BIAS, bool TRAIT>
__global__ __launch_bounds__(256) void k_mgemm(const unsigned short* __restrict__ ah,
                                               const unsigned short* __restrict__ al,
                                               const unsigned short* __restrict__ bh,
                                               const unsigned short* __restrict__ bl,
                                               const float* __restrict__ bias,
                                               const float* __restrict__ wtrait,
                                               const float* __restrict__ tt,
                                               float* __restrict__ C,
                                               int N, int Kd) {
    __shared__ unsigned short Ah[128*40], Al[128*40], Bh[64*40], Bl[64*40];
    int bn = blockIdx.x * 64;
    int bm = blockIdx.y * 128;
    int tid = threadIdx.x;
    int lane = tid & 63, wv = tid >> 6;
    int mbase = (wv >> 1)*64, nbase = (wv & 1)*32;
    int fr = lane & 15, kg = lane >> 4;
    floatx4 acc[4][2];
#pragma unroll
    for (int mi = 0; mi < 4; ++mi)
#pragma unroll
        for (int ni = 0; ni < 2; ++ni)
            acc[mi][ni] = (floatx4){0.f, 0.f, 0.f, 0.f};

    for (int k0 = 0; k0 < Kd; k0 += 32) {
#pragma unroll
        for (int f = 0; f < 2; ++f) {
            int v = f*256 + tid;
            int r = v >> 2, kq = v & 3;
            size_t g = (size_t)(bm + r)*Kd + k0 + kq*8;
            int off = r*40 + kq*8;
            *(int4*)(Ah + off) = *(const int4*)(ah + g);
            *(int4*)(Al + off) = *(const int4*)(al + g);
        }
        {
            int r = tid >> 2, kq = tid & 3;
            size_t g = (size_t)(bn + r)*Kd + k0 + kq*8;
            int off = r*40 + kq*8;
            *(int4*)(Bh + off) = *(const int4*)(bh + g);
            *(int4*)(Bl + off) = *(const int4*)(bl + g);
        }
        __syncthreads();

        bf16x8 bhf[2], blf[2];
#pragma unroll
        for (int ni = 0; ni < 2; ++ni) {
            int off = (nbase + ni*16 + fr)*40 + kg*8;
            bhf[ni] = *(const bf16x8*)(Bh + off);
            blf[ni] = *(const bf16x8*)(Bl + off);
        }
#pragma unroll
        for (int mi = 0; mi < 4; ++mi) {
            int off = (mbase + mi*16 + fr)*40 + kg*8;
            bf16x8 ahf = *(const bf16x8*)(Ah + off);
            bf16x8 alf = *(const bf16x8*)(Al + off);
#pragma unroll
            for (int ni = 0; ni < 2; ++ni) {
                floatx4 c = acc[mi][ni];
                c = __builtin_amdgcn_mfma_f32_16x16x32_bf16(ahf, bhf[ni], c, 0, 0, 0);
                c = __builtin_amdgcn_mfma_f32_16x16x32_bf16(alf, bhf[ni], c, 0, 0, 0);
                c = __builtin_amdgcn_mfma_f32_16x16x32_bf16(ahf, blf[ni], c, 0, 0, 0);
                acc[mi][ni] = c;
            }
        }
        __syncthreads();
    }
#pragma unroll
    for (int mi = 0; mi < 4; ++mi) {
        int m0 = bm + mbase + mi*16 + kg*4;
#pragma unroll
        for (int ni = 0; ni < 2; ++ni) {
            int n = bn + nbase + ni*16 + fr;
#pragma unroll
            for (int r = 0; r < 4; ++r) {
                float v = acc[mi][ni][r];
                if (TRAIT) v += tt[m0 + r] * wtrait[n];
                if (BIAS)  v += bias[n];
                size_t o = (size_t)(m0 + r)*N + n;
                if (ADD) C[o] += v; else C[o] = v;
            }
        }
    }
}

// layer norm -> fp32 out + bf16 hi/lo planes
__global__ __launch_bounds__(256) void k_ln(const float* __restrict__ x,
                                            const float* __restrict__ g,
                                            const float* __restrict__ b,
                                            float* __restrict__ xn,
                                            unsigned short* __restrict__ xnh,
                                            unsigned short* __restrict__ xnl) {
    int row = blockIdx.x, tid = threadIdx.x;
    float v = x[(size_t)row*H_ + tid];
    float mean = block_reduce_sum(v) * (1.f/H_);
    float d = v - mean;
    float var = block_reduce_sum(d*d) * (1.f/H_);
    float o = d * rsqrtf(var + 1e-5f) * g[tid] + b[tid];
    size_t oo = (size_t)row*H_ + tid;
    xn[oo] = o;
    unsigned short h = f2bf(o);
    xnh[oo] = h; xnl[oo] = f2bf(o - bf2f(h));
}

// fused mamba inner chain: conv+silu -> dbl (MFMA) -> dt -> selective scan -> gate.
// block = one sequence (n), 512 threads = one per d channel.
// LDS: xc [9][516] (padded), dbl [9][48].  Wx^T pre-converted to bf16 hi/lo planes.
__global__ __launch_bounds__(512) void k_mamba(const float* __restrict__ xz,
                                               const float* __restrict__ cw,
                                               const float* __restrict__ cb,
                                               const unsigned short* __restrict__ wxh,
                                               const unsigned short* __restrict__ wxl,
                                               const float* __restrict__ Wdt,
                                               const float* __restrict__ bdt,
                                               const float* __restrict__ A_log,
                                               const float* __restrict__ Dp,
                                               unsigned short* __restrict__ yh,
                                               unsigned short* __restrict__ yl) {
    __shared__ float xcS[L_][516];
    __shared__ float dblS[L_][48];
    int n = blockIdx.x, d = threadIdx.x;

    // ---- causal conv (KC=4) + silu; keep xc and z in registers ----
    float c0 = cw[d*4+0], c1 = cw[d*4+1], c2 = cw[d*4+2], c3 = cw[d*4+3];
    float bb = cb[d];
    const float* src = xz + (size_t)n*L_*(2*DI_) + d;
    float xc[L_], z[L_];
    float x0 = 0.f, x1 = 0.f, x2 = 0.f;
#pragma unroll
    for (int l = 0; l < L_; ++l) {
        float x3 = src[l*(2*DI_)];
        z[l]     = src[l*(2*DI_) + DI_];
        float s = bb + c0*x0 + c1*x1 + c2*x2 + c3*x3;
        float v = siluf_(s);
        xc[l] = v; xcS[l][d] = v;
        x0 = x1; x1 = x2; x2 = x3;
    }
    __syncthreads();

    // ---- dbl = xc(9x512) @ Wx(512x48) via split-bf16 MFMA on waves 0..2 ----
    int wv = d >> 6, lane = d & 63;
    if (wv < 3) {
        int fr = lane & 15, kg = lane >> 4;
        const unsigned short* bph = wxh + (size_t)(wv*16 + fr)*DI_;
        const unsigned short* bpl = wxl + (size_t)(wv*16 + fr)*DI_;
        floatx4 c = (floatx4){0.f, 0.f, 0.f, 0.f};
        for (int k0 = 0; k0 < DI_; k0 += 32) {
            int kb = k0 + kg*8;
            float av[8];
            if (fr < L_) {
                float4 q0 = *(const float4*)(&xcS[fr][kb]);
                float4 q1 = *(const float4*)(&xcS[fr][kb+4]);
                av[0]=q0.x; av[1]=q0.y; av[2]=q0.z; av[3]=q0.w;
                av[4]=q1.x; av[5]=q1.y; av[6]=q1.z; av[7]=q1.w;
            } else {
#pragma unroll
                for (int j = 0; j < 8; ++j) av[j] = 0.f;
            }
            bf16x8 ah, al;
#pragma unroll
            for (int j = 0; j < 8; ++j) {
                unsigned short hh = f2bf(av[j]);
                ah[j] = (short)hh;
                al[j] = (short)f2bf(av[j] - bf2f(hh));
            }
            bf16x8 bhf = *(const bf16x8*)(bph + kb);
            bf16x8 blf = *(const bf16x8*)(bpl + kb);
            c = __builtin_amdgcn_mfma_f32_16x16x32_bf16(ah, bhf, c, 0, 0, 0);
            c = __builtin_amdgcn_mfma_f32_16x16x32_bf16(al, bhf, c, 0, 0, 0);
            c = __builtin_amdgcn_mfma_f32_16x16x32_bf16(ah, blf, c, 0, 0, 0);
        }
#pragma unroll
        for (int r = 0; r < 4; ++r) {
            int row = kg*4 + r;
            if (row < L_) dblS[row][wv*16 + fr] = c[r];
        }
    }
    __syncthreads();

    // ---- dt + selective scan + gate, per-thread channel d ----
    float a[S_], wdt[R_];
#pragma unroll
    for (int s = 0; s < S_; ++s) a[s] = -expf(A_log[(size_t)d*S_ + s]);
#pragma unroll
    for (int r = 0; r < R_; ++r) wdt[r] = Wdt[(size_t)r*DI_ + d];
    float bdtv = bdt[d], dp = Dp[d];
    float h[S_];
#pragma unroll
    for (int s = 0; s < S_; ++s) h[s] = 0.f;
    size_t ob = (size_t)n*L_*DI_ + d;
#pragma unroll
    for (int l = 0; l < L_; ++l) {
        float s = bdtv;
#pragma unroll
        for (int r = 0; r < R_; ++r) s = fmaf(dblS[l][r], wdt[r], s);
        float dtv = softplusf_(s);
        float xcv = xc[l];
        float accv = 0.f;
#pragma unroll
        for (int si = 0; si < S_; ++si) {
            float Bv = dblS[l][16 + si], Cv = dblS[l][32 + si];
            h[si] = expf(dtv*a[si])*h[si] + dtv*Bv*xcv;
            accv = fmaf(h[si], Cv, accv);
        }
        float yv = (accv + dp*xcv) * siluf_(z[l]);
        unsigned short hh = f2bf(yv);
        yh[ob + (size_t)l*DI_] = hh;
        yl[ob + (size_t)l*DI_] = f2bf(yv - bf2f(hh));
    }
}

// head
__global__ __launch_bounds__(128) void k_head(const float* __restrict__ x,
                                              const float* __restrict__ W1,
                                              const float* __restrict__ b1,
                                              const float* __restrict__ W2,
                                              const float* __restrict__ b2,
                                              float* __restrict__ out) {
    int n = blockIdx.x, tid = threadIdx.x;
    __shared__ float ms[H_];
    const float* src = x + ((size_t)n*L_ + (L_-1))*H_;
    ms[tid] = src[tid];
    ms[tid+128] = src[tid+128];
    __syncthreads();
    float s = b1[tid];
#pragma unroll 8
    for (int k = 0; k < H_; ++k) s = fmaf(ms[k], W1[(size_t)k*128 + tid], s);
    float h = fmaxf(s, 0.f);
    float p = h * W2[tid];
    float tot = block_reduce_sum(p);
    if (tid == 0) out[n] = tot + b2[0];
}

// ---------------- launch ----------------

extern "C" void kernel_launch(void* const* d_in, const int* in_sizes, int n_in,
                              void* d_out, int out_size, void* d_ws, size_t ws_size,
                              hipStream_t stream) {
    const float* unl   = (const float*)d_in[0];
    const float* lab_e = (const float*)d_in[1];
    const float* lab_t = (const float*)d_in[2];
    const float* mlog  = (const float*)d_in[3];
    const float* Wp    = (const float*)d_in[4];
    const float* bp    = (const float*)d_in[5];
    const float* ln_g  = (const float*)d_in[6];
    const float* ln_b  = (const float*)d_in[7];
    const float* Win   = (const float*)d_in[8];
    const float* conv_w= (const float*)d_in[9];
    const float* conv_b= (const float*)d_in[10];
    const float* Wx    = (const float*)d_in[11];
    const float* Wdt   = (const float*)d_in[12];
    const float* bdt   = (const float*)d_in[13];
    const float* A_log = (const float*)d_in[14];
    const float* Dp    = (const float*)d_in[15];
    const float* Wout  = (const float*)d_in[16];
    const float* W1    = (const float*)d_in[17];
    const float* b1    = (const float*)d_in[18];
    const float* W2    = (const float*)d_in[19];
    const float* b2    = (const float*)d_in[20];

    float* ws = (float*)d_ws;
    // fixed layout (float units); ushort buffers cast from 4-aligned float offsets
    float* w    = ws + 0;                                    // 16
    int*   idx  = (int*)(ws + 16);                           // 10240 ints
    float* uc   = ws + 10256;                                // 196,608
    // old rn slot (100,000 floats) repurposed for Wx^T bf16 planes (4 layers)
    unsigned short* wxth = (unsigned short*)(ws + 206864);   // 98,304 ush = 49,152 f
    unsigned short* wxtl = (unsigned short*)(ws + 256016);   // 98,304 ush
    float* tt   = ws + 306864;                               // 11,520
    unsigned short* qnh   = (unsigned short*)(ws + 318384);  // 983,040 ush
    unsigned short* qnl   = (unsigned short*)(ws + 809904);
    unsigned short* wph   = (unsigned short*)(ws + 1301424); // 196,608 ush
    unsigned short* wpl   = (unsigned short*)(ws + 1399728);
    unsigned short* winh  = (unsigned short*)(ws + 1498032); // 1,048,576 ush
    unsigned short* winl  = (unsigned short*)(ws + 2022320);
    unsigned short* wouth = (unsigned short*)(ws + 2546608); // 524,288 ush
    unsigned short* woutl = (unsigned short*)(ws + 2808752);
    float* xa   = ws + 3070896;                              // 2,949,120
    float* xb   = ws + 6020016;                              // 2,949,120
    unsigned short* xnh   = (unsigned short*)(ws + 8969136); // 2,949,120 ush
    unsigned short* xnl   = (unsigned short*)(ws + 10443696);
    float* simreg = ws + 18369456;                           // 25,600,000
    float* sim  = simreg;
    float* xz   = simreg;                                    // 11,796,480 (phase 2)
    unsigned short* tokh = (unsigned short*)(simreg + 11796480); // 8,847,360 ush (dead before xz phase-2 grows)
    unsigned short* tokl = (unsigned short*)(simreg + 16220160);
    unsigned short* yh   = (unsigned short*)(simreg + 17694720); // 5,898,240 ush
    unsigned short* yl   = (unsigned short*)(simreg + 20643840);

    k_softmax_w<<<1, 64, 0, stream>>>(mlog, w);
    k_qn_uc<<<B_, 256, 0, stream>>>(unl, w, qnh, qnl, uc);
    // weight conversions (once per call)
    k_cvtw<<<(768*256 + 255)/256, 256, 0, stream>>>(Wp, wph, wpl, 768, 256);
    for (int i = 0; i < NL_; ++i) {
        k_cvtw<<<(256*1024 + 255)/256, 256, 0, stream>>>(Win + (size_t)i*H_*(2*DI_),
                                                         winh + (size_t)i*H_*(2*DI_),
                                                         winl + (size_t)i*H_*(2*DI_), 256, 1024);
        k_cvtw<<<(512*256 + 255)/256, 256, 0, stream>>>(Wout + (size_t)i*DI_*H_,
                                                        wouth + (size_t)i*DI_*H_,
                                                        woutl + (size_t)i*DI_*H_, 512, 256);
        k_cvtw<<<(512*48 + 255)/256, 256, 0, stream>>>(Wx + (size_t)i*DI_*48,
                                                       wxth + (size_t)i*48*DI_,
                                                       wxtl + (size_t)i*48*DI_, 512, 48);
    }
    k_simf<<<1600, 512, 0, stream>>>(qnh, qnl, lab_e, w, sim);
    {
        dim3 g(B_, T_);
        k_topk<<<g, 256, 0, stream>>>(sim, idx);
    }
    k_toks<<<NROW, 256, 0, stream>>>(lab_e, lab_t, uc, idx, tokh, tokl, tt);
    {
        dim3 g(H_/64, NROW/128);
        k_mgemm<false,true,true><<<g, 256, 0, stream>>>(tokh, tokl, wph, wpl,
                                                        bp, Wp + (size_t)768*H_, tt, xa, H_, D_);
    }
    float* cur = xa;
    float* oth = xb;
    for (int i = 0; i < NL_; ++i) {
        k_ln<<<NROW, 256, 0, stream>>>(cur, ln_g + (size_t)i*H_, ln_b + (size_t)i*H_, oth, xnh, xnl);
        {
            dim3 g((2*DI_)/64, NROW/128);
            k_mgemm<false,false,false><<<g, 256, 0, stream>>>(xnh, xnl,
                winh + (size_t)i*H_*(2*DI_), winl + (size_t)i*H_*(2*DI_),
                nullptr, nullptr, nullptr, xz, 2*DI_, H_);
        }
        k_mamba<<<NBT, 512, 0, stream>>>(xz,
                                         conv_w + (size_t)i*DI_*KC_, conv_b + (size_t)i*DI_,
                                         wxth + (size_t)i*48*DI_, wxtl + (size_t)i*48*DI_,
                                         Wdt + (size_t)i*R_*DI_, bdt + (size_t)i*DI_,
                                         A_log + (size_t)i*DI_*S_, Dp + (size_t)i*DI_,
                                         yh, yl);
        {
            dim3 g(H_/64, NROW/128);
            k_mgemm<true,false,false><<<g, 256, 0, stream>>>(yh, yl,
                wouth + (size_t)i*DI_*H_, woutl + (size_t)i*DI_*H_,
                nullptr, nullptr, nullptr, oth, H_, DI_);
        }
        float* tmp = cur; cur = oth; oth = tmp;
    }
    k_head<<<NBT, 128, 0, stream>>>(cur, W1, b1, W2, b2, (float*)d_out);
}